// Round 3
// baseline (1613.833 us; speedup 1.0000x reference)
//
#include <hip/hip_runtime.h>
#include <hip/hip_bf16.h>

// Fused FeedForward_denoise: project_in (1x1), project_in_pn (1x1), two grouped
// 3x3 convs, depthwise 3x3, exact-GELU gating, grouped 1x1 project_out.
// All global tensors fp32 (per reference); fp32 accumulation; xc staged in LDS
// as bf16 (error ~1e-4 vs 2.9e-3 threshold).
//
// Tile: 16x16 output pixels per block. Halo-2 region (20x20) of xc channels is
// computed in LDS per channel-chunk (4 gate pairs -> 8 dw channels -> 24 xc ch).

#define T 16
#define R20 20
#define R18 18

typedef unsigned short u16;
typedef unsigned int u32;

__device__ __forceinline__ float bflo(u32 w) {
    union { u32 i; float f; } v; v.i = w << 16; return v.f;
}
__device__ __forceinline__ float bfhi(u32 w) {
    union { u32 i; float f; } v; v.i = w & 0xffff0000u; return v.f;
}
__device__ __forceinline__ u16 f2bf(float f) {
    union { float f; u32 i; } v; v.f = f;
    u32 x = v.i;
    u32 r = (x + 0x7fffu + ((x >> 16) & 1u)) >> 16;
    return (u16)r;
}
__device__ __forceinline__ float gelu_exact(float v) {
    return 0.5f * v * (1.0f + erff(v * 0.70710678118654752f));
}

__global__ __launch_bounds__(256, 2)
void ffd_fused(const float* __restrict__ xin,      // [4][64][256][256]
               const float* __restrict__ pnin,     // [4][2][256][256]
               const float* __restrict__ w_in,     // [256][64]
               const float* __restrict__ b_in,     // [256]
               const float* __restrict__ w_pn,     // [128][2]
               const float* __restrict__ b_pn,     // [128]
               const float* __restrict__ w_dw1,    // [128][3][3][3]
               const float* __restrict__ b_dw1,    // [128]
               const float* __restrict__ w_dw3a,   // [128][3][3][3]
               const float* __restrict__ b_dw3a,   // [128]
               const float* __restrict__ w_dw3b,   // [128][1][3][3]
               const float* __restrict__ b_dw3b,   // [128]
               const float* __restrict__ w_out,    // [64][64]
               const float* __restrict__ b_out,    // [64]
               float* __restrict__ outp)           // [4][64][256][256]
{
    __shared__ __align__(8) u16 s_xc[24][R20 * R20];   // chunk xc channels, bf16
    __shared__ __align__(8) float s_d3a[8][R18 * R18];
    __shared__ float s_d1[8][T * T];
    __shared__ float s_d3[8][T * T];
    __shared__ float s_wd1[8][27];
    __shared__ float s_wd3a[8][27];
    __shared__ float s_wd3b[8][9];
    __shared__ float s_b1[8], s_b3a[8], s_b3b[8];

    const int tid = threadIdx.x;
    const int ox0 = blockIdx.x * T;
    const int oy0 = blockIdx.y * T;
    const int b   = blockIdx.z;

    float accL[32], accH[32];
#pragma unroll
    for (int o = 0; o < 32; ++o) { accL[o] = 0.f; accH[o] = 0.f; }

    for (int chunk = 0; chunk < 16; ++chunk) {
        const int c0 = chunk * 4;
        __syncthreads();   // protect s_* reuse across chunks

        // ---- Phase W: stage chunk weights into LDS -------------------------
        for (int t = tid; t < 512; t += 256) {
            if (t < 216) {
                int gl = t / 27, idx = t - gl * 27;
                int g = (gl < 4) ? (c0 + gl) : (c0 + 60 + gl);
                s_wd1[gl][idx] = w_dw1[g * 27 + idx];
            } else if (t < 432) {
                int t2 = t - 216;
                int gl = t2 / 27, idx = t2 - gl * 27;
                int g = (gl < 4) ? (c0 + gl) : (c0 + 60 + gl);
                s_wd3a[gl][idx] = w_dw3a[g * 27 + idx];
            } else if (t < 504) {
                int t2 = t - 432;
                int gl = t2 / 9, idx = t2 - gl * 9;
                int g = (gl < 4) ? (c0 + gl) : (c0 + 60 + gl);
                s_wd3b[gl][idx] = w_dw3b[g * 9 + idx];
            } else {
                int gl = t - 504;
                int g = (gl < 4) ? (c0 + gl) : (c0 + 60 + gl);
                s_b1[gl]  = b_dw1[g];
                s_b3a[gl] = b_dw3a[g];
                s_b3b[gl] = b_dw3b[g];
            }
        }

        // ---- Phase A: xc channels for chunk over 20x20 halo region ---------
        for (int p = tid; p < R20 * R20; p += 256) {
            int py = p / R20, px = p - py * R20;
            int gy = oy0 - 2 + py, gx = ox0 - 2 + px;
            if ((unsigned)gy >= 256u || (unsigned)gx >= 256u) {
                // conv zero-padding: xc == 0 outside the image
#pragma unroll 1
                for (int l = 0; l < 24; ++l) s_xc[l][p] = 0;
                continue;
            }
            const int off = gy * 256 + gx;
            float xr[64];
            const float* xp = xin + (size_t)b * 64 * 65536 + off;
#pragma unroll
            for (int c = 0; c < 64; ++c) xr[c] = xp[(size_t)c * 65536];
            float p0 = 0.f, p1 = 0.f;
            if (3 * c0 < 128) {   // chunk contains pn channels
                const float* pp = pnin + (size_t)b * 2 * 65536 + off;
                p0 = pp[0]; p1 = pp[65536];
            }
#pragma unroll 1
            for (int l = 0; l < 24; ++l) {
                int k = (l < 12) ? (3 * c0 + l) : (3 * c0 + 192 + (l - 12));
                float acc;
                if (k < 128) {
                    acc = b_pn[k] + w_pn[2 * k] * p0 + w_pn[2 * k + 1] * p1;
                } else {
                    int kk = k - 128;
                    acc = b_in[kk];
                    const float2* wr = (const float2*)(w_in + kk * 64);
#pragma unroll
                    for (int i = 0; i < 32; ++i) {
                        float2 w2 = wr[i];
                        acc = fmaf(w2.x, xr[2 * i], acc);
                        acc = fmaf(w2.y, xr[2 * i + 1], acc);
                    }
                }
                s_xc[l][p] = f2bf(acc);
            }
        }
        __syncthreads();

        // ---- Phase B1a: d3a (grouped 3x3) over 18x18, 2x2 per thread -------
        for (int task = tid; task < 8 * 81; task += 256) {
            int gl = task / 81, patch = task - gl * 81;
            int py = (patch / 9) * 2, px = (patch - (patch / 9) * 9) * 2; // region18
            float bias = s_b3a[gl];
            float a00 = bias, a01 = bias, a10 = bias, a11 = bias;
#pragma unroll
            for (int j = 0; j < 3; ++j) {
                int lc = (gl < 4) ? (3 * gl + j) : (12 + 3 * (gl - 4) + j);
                const u32* base = (const u32*)&s_xc[lc][0];
                float win[4][4];
#pragma unroll
                for (int r = 0; r < 4; ++r) {
                    int e = (py + r) * R20 + px;   // even
                    u32 u0 = base[e >> 1];
                    u32 u1 = base[(e >> 1) + 1];
                    win[r][0] = bflo(u0); win[r][1] = bfhi(u0);
                    win[r][2] = bflo(u1); win[r][3] = bfhi(u1);
                }
#pragma unroll
                for (int ky = 0; ky < 3; ++ky)
#pragma unroll
                    for (int kx = 0; kx < 3; ++kx) {
                        float wgt = s_wd3a[gl][j * 9 + ky * 3 + kx];
                        a00 = fmaf(wgt, win[ky][kx], a00);
                        a01 = fmaf(wgt, win[ky][kx + 1], a01);
                        a10 = fmaf(wgt, win[ky + 1][kx], a10);
                        a11 = fmaf(wgt, win[ky + 1][kx + 1], a11);
                    }
            }
            // zero out-of-image outputs (they are padding for dwconvIII[1])
            int gy0 = oy0 - 1 + py, gx0 = ox0 - 1 + px;
            bool vy0 = (unsigned)gy0 < 256u, vy1 = (unsigned)(gy0 + 1) < 256u;
            bool vx0 = (unsigned)gx0 < 256u, vx1 = (unsigned)(gx0 + 1) < 256u;
            float* drow = &s_d3a[gl][py * R18 + px];
            drow[0]       = (vy0 && vx0) ? a00 : 0.f;
            drow[1]       = (vy0 && vx1) ? a01 : 0.f;
            drow[R18]     = (vy1 && vx0) ? a10 : 0.f;
            drow[R18 + 1] = (vy1 && vx1) ? a11 : 0.f;
        }

        // ---- Phase B1b: d1 (grouped 3x3) over interior 16x16, 2x2/thread ---
        for (int task = tid; task < 8 * 64; task += 256) {
            int gl = task >> 6, patch = task & 63;
            int py = (patch >> 3) * 2, px = (patch & 7) * 2;   // interior coords
            float bias = s_b1[gl];
            float a00 = bias, a01 = bias, a10 = bias, a11 = bias;
#pragma unroll
            for (int j = 0; j < 3; ++j) {
                int lc = (gl < 4) ? (3 * gl + j) : (12 + 3 * (gl - 4) + j);
                const u32* base = (const u32*)&s_xc[lc][0];
                float win[4][4];
#pragma unroll
                for (int r = 0; r < 4; ++r) {
                    int e = (py + 1 + r) * R20 + px;   // even; need cols px+1..px+4
                    u32 u0 = base[e >> 1];
                    u32 u1 = base[(e >> 1) + 1];
                    u32 u2 = base[(e >> 1) + 2];
                    win[r][0] = bfhi(u0); win[r][1] = bflo(u1);
                    win[r][2] = bfhi(u1); win[r][3] = bflo(u2);
                }
#pragma unroll
                for (int ky = 0; ky < 3; ++ky)
#pragma unroll
                    for (int kx = 0; kx < 3; ++kx) {
                        float wgt = s_wd1[gl][j * 9 + ky * 3 + kx];
                        a00 = fmaf(wgt, win[ky][kx], a00);
                        a01 = fmaf(wgt, win[ky][kx + 1], a01);
                        a10 = fmaf(wgt, win[ky + 1][kx], a10);
                        a11 = fmaf(wgt, win[ky + 1][kx + 1], a11);
                    }
            }
            float* drow = &s_d1[gl][py * T + px];
            drow[0] = a00; drow[1] = a01; drow[T] = a10; drow[T + 1] = a11;
        }
        __syncthreads();

        // ---- Phase B2: d3 = depthwise 3x3 over d3a, interior, 2x2/thread ---
        for (int task = tid; task < 8 * 64; task += 256) {
            int gl = task >> 6, patch = task & 63;
            int py = (patch >> 3) * 2, px = (patch & 7) * 2;
            float bias = s_b3b[gl];
            float a00 = bias, a01 = bias, a10 = bias, a11 = bias;
            float win[4][4];
#pragma unroll
            for (int r = 0; r < 4; ++r) {
                int e = (py + r) * R18 + px;   // even, 8B aligned
                float2 f0 = *(const float2*)&s_d3a[gl][e];
                float2 f1 = *(const float2*)&s_d3a[gl][e + 2];
                win[r][0] = f0.x; win[r][1] = f0.y;
                win[r][2] = f1.x; win[r][3] = f1.y;
            }
#pragma unroll
            for (int ky = 0; ky < 3; ++ky)
#pragma unroll
                for (int kx = 0; kx < 3; ++kx) {
                    float wgt = s_wd3b[gl][ky * 3 + kx];
                    a00 = fmaf(wgt, win[ky][kx], a00);
                    a01 = fmaf(wgt, win[ky][kx + 1], a01);
                    a10 = fmaf(wgt, win[ky + 1][kx], a10);
                    a11 = fmaf(wgt, win[ky + 1][kx + 1], a11);
                }
            float* drow = &s_d3[gl][py * T + px];
            drow[0] = a00; drow[1] = a01; drow[T] = a10; drow[T + 1] = a11;
        }
        __syncthreads();

        // ---- Phase C: gating + grouped project_out accumulation ------------
#pragma unroll
        for (int jp = 0; jp < 2; ++jp) {
            int j0 = 2 * jp;
            float g1a = gelu_exact(s_d1[j0][tid])     * s_d1[j0 + 4][tid];
            float g1b = gelu_exact(s_d1[j0 + 1][tid]) * s_d1[j0 + 5][tid];
            float g2a = gelu_exact(s_d3[j0][tid])     * s_d3[j0 + 4][tid];
            float g2b = gelu_exact(s_d3[j0 + 1][tid]) * s_d3[j0 + 5][tid];
            int c = c0 + j0;   // even
#pragma unroll
            for (int o = 0; o < 32; ++o) {
                float2 wL = *(const float2*)(w_out + o * 64 + c);
                accL[o] = fmaf(wL.x, g1a, accL[o]);
                accL[o] = fmaf(wL.y, g1b, accL[o]);
                float2 wH = *(const float2*)(w_out + (o + 32) * 64 + c);
                accH[o] = fmaf(wH.x, g2a, accH[o]);
                accH[o] = fmaf(wH.y, g2b, accH[o]);
            }
        }
    }

    // ---- Epilogue: bias + fp32 store --------------------------------------
    {
        int py = tid >> 4, pxx = tid & 15;
        size_t obase = (size_t)b * 64 * 65536
                     + (size_t)(oy0 + py) * 256 + (ox0 + pxx);
#pragma unroll
        for (int o = 0; o < 32; ++o) {
            outp[obase + (size_t)o * 65536]        = accL[o] + b_out[o];
            outp[obase + (size_t)(o + 32) * 65536] = accH[o] + b_out[o + 32];
        }
    }
}

extern "C" void kernel_launch(void* const* d_in, const int* in_sizes, int n_in,
                              void* d_out, int out_size, void* d_ws, size_t ws_size,
                              hipStream_t stream) {
    (void)in_sizes; (void)n_in; (void)d_ws; (void)ws_size; (void)out_size;
    const float* xin    = (const float*)d_in[0];
    const float* pnin   = (const float*)d_in[1];
    const float* w_in   = (const float*)d_in[2];
    const float* b_in   = (const float*)d_in[3];
    const float* w_pn   = (const float*)d_in[4];
    const float* b_pn   = (const float*)d_in[5];
    const float* w_dw1  = (const float*)d_in[6];
    const float* b_dw1  = (const float*)d_in[7];
    const float* w_dw3a = (const float*)d_in[8];
    const float* b_dw3a = (const float*)d_in[9];
    const float* w_dw3b = (const float*)d_in[10];
    const float* b_dw3b = (const float*)d_in[11];
    const float* w_out  = (const float*)d_in[12];
    const float* b_out  = (const float*)d_in[13];
    float* outp = (float*)d_out;

    dim3 grid(16, 16, 4);   // W/16, H/16, B
    dim3 block(256);
    ffd_fused<<<grid, block, 0, stream>>>(xin, pnin, w_in, b_in, w_pn, b_pn,
                                          w_dw1, b_dw1, w_dw3a, b_dw3a,
                                          w_dw3b, b_dw3b, w_out, b_out, outp);
}

// Round 4
// 1220.157 us; speedup vs baseline: 1.3226x; 1.3226x over previous
//
#include <hip/hip_runtime.h>
#include <hip/hip_bf16.h>

// Two-phase FeedForward_denoise:
//   K1: 1x1 projections (project_in 64->256, project_in_pn 2->128) -> xc bf16
//       in d_ws, layout [B][384][H][W]. Reads x exactly once (round-3 kernel
//       was HBM-bound refetching x 16x: FETCH 2.6 GB ~= dur 1.6 ms).
//   K2: per 16x16 tile, load 24 xc channels/chunk from d_ws, grouped 3x3 convs,
//       depthwise 3x3, exact-GELU gating, grouped 1x1 project_out.
// Fallback to the fully-fused round-3 kernel if ws_size < 201 MB.

#define T 16
#define R20 20
#define R18 18
#define XC_CH 384
#define HW 65536
#define XC_BYTES ((size_t)4 * XC_CH * HW * 2)

typedef unsigned short u16;
typedef unsigned int u32;

__device__ __forceinline__ float bflo(u32 w) {
    union { u32 i; float f; } v; v.i = w << 16; return v.f;
}
__device__ __forceinline__ float bfhi(u32 w) {
    union { u32 i; float f; } v; v.i = w & 0xffff0000u; return v.f;
}
__device__ __forceinline__ float bf2f(u16 u) {
    union { u32 i; float f; } v; v.i = ((u32)u) << 16; return v.f;
}
__device__ __forceinline__ u16 f2bf(float f) {
    union { float f; u32 i; } v; v.f = f;
    u32 x = v.i;
    u32 r = (x + 0x7fffu + ((x >> 16) & 1u)) >> 16;
    return (u16)r;
}
__device__ __forceinline__ float gelu_exact(float v) {
    return 0.5f * v * (1.0f + erff(v * 0.70710678118654752f));
}

// ---------------------------------------------------------------------------
// K1: per-pixel 1x1 projections. One thread = one pixel; w rows wave-uniform
// (scalarized by compiler). 2-row unroll for FMA ILP.
// ---------------------------------------------------------------------------
__global__ __launch_bounds__(256, 4)
void k1_proj_in(const float* __restrict__ xin,   // [4][64][256][256]
                const float* __restrict__ pnin,  // [4][2][256][256]
                const float* __restrict__ w_in,  // [256][64]
                const float* __restrict__ b_in,  // [256]
                const float* __restrict__ w_pn,  // [128][2]
                const float* __restrict__ b_pn,  // [128]
                u16* __restrict__ xc)            // [4][384][256][256] bf16
{
    const int b = blockIdx.y;
    const int p = blockIdx.x * 256 + threadIdx.x;   // 0..65535

    float xr[64];
    const float* xp = xin + (size_t)b * 64 * HW + p;
#pragma unroll
    for (int c = 0; c < 64; ++c) xr[c] = xp[(size_t)c * HW];

    const float p0 = pnin[(size_t)b * 2 * HW + p];
    const float p1 = pnin[(size_t)b * 2 * HW + HW + p];

    u16* xcb = xc + (size_t)b * XC_CH * HW + p;

    // pn part: xc[0..127]
#pragma unroll 4
    for (int i = 0; i < 128; ++i) {
        float acc = fmaf(w_pn[2 * i], p0, fmaf(w_pn[2 * i + 1], p1, b_pn[i]));
        xcb[(size_t)i * HW] = f2bf(acc);
    }
    // xi part: xc[128..383], two output rows at a time (ILP)
    for (int j = 0; j < 256; j += 2) {
        float a0 = b_in[j], a1 = b_in[j + 1];
        const float* w0 = w_in + j * 64;
        const float* w1 = w0 + 64;
#pragma unroll
        for (int c = 0; c < 64; ++c) {
            a0 = fmaf(w0[c], xr[c], a0);
            a1 = fmaf(w1[c], xr[c], a1);
        }
        xcb[(size_t)(128 + j) * HW] = f2bf(a0);
        xcb[(size_t)(129 + j) * HW] = f2bf(a1);
    }
}

// ---------------------------------------------------------------------------
// K2: spatial convs + gating + project_out, xc streamed from d_ws.
// ---------------------------------------------------------------------------
__global__ __launch_bounds__(256, 3)
void k2_spatial(const u16* __restrict__ xc,      // [4][384][256][256] bf16
                const float* __restrict__ w_dw1,  const float* __restrict__ b_dw1,
                const float* __restrict__ w_dw3a, const float* __restrict__ b_dw3a,
                const float* __restrict__ w_dw3b, const float* __restrict__ b_dw3b,
                const float* __restrict__ w_out,  const float* __restrict__ b_out,
                float* __restrict__ outp)         // [4][64][256][256]
{
    __shared__ __align__(8) u16 s_xc[24][R20 * R20];
    __shared__ __align__(8) float s_d3a[8][R18 * R18];
    __shared__ float s_d1[8][T * T];
    __shared__ float s_d3[8][T * T];
    __shared__ float s_wd1[8][27];
    __shared__ float s_wd3a[8][27];
    __shared__ float s_wd3b[8][9];
    __shared__ float s_b1[8], s_b3a[8], s_b3b[8];

    const int tid = threadIdx.x;
    const int ox0 = blockIdx.x * T;
    const int oy0 = blockIdx.y * T;
    const int b   = blockIdx.z;

    const u16* xcb = xc + (size_t)b * XC_CH * HW;

    float accL[32], accH[32];
#pragma unroll
    for (int o = 0; o < 32; ++o) { accL[o] = 0.f; accH[o] = 0.f; }

    for (int chunk = 0; chunk < 16; ++chunk) {
        const int c0 = chunk * 4;
        __syncthreads();   // protect s_* reuse across chunks

        // ---- Phase W: stage chunk weights into LDS -------------------------
        for (int t = tid; t < 512; t += 256) {
            if (t < 216) {
                int gl = t / 27, idx = t - gl * 27;
                int g = (gl < 4) ? (c0 + gl) : (c0 + 60 + gl);
                s_wd1[gl][idx] = w_dw1[g * 27 + idx];
            } else if (t < 432) {
                int t2 = t - 216;
                int gl = t2 / 27, idx = t2 - gl * 27;
                int g = (gl < 4) ? (c0 + gl) : (c0 + 60 + gl);
                s_wd3a[gl][idx] = w_dw3a[g * 27 + idx];
            } else if (t < 504) {
                int t2 = t - 432;
                int gl = t2 / 9, idx = t2 - gl * 9;
                int g = (gl < 4) ? (c0 + gl) : (c0 + 60 + gl);
                s_wd3b[gl][idx] = w_dw3b[g * 9 + idx];
            } else {
                int gl = t - 504;
                int g = (gl < 4) ? (c0 + gl) : (c0 + 60 + gl);
                s_b1[gl]  = b_dw1[g];
                s_b3a[gl] = b_dw3a[g];
                s_b3b[gl] = b_dw3b[g];
            }
        }

        // ---- Phase A: load chunk's 24 xc channels over 20x20 halo ----------
        for (int idx = tid; idx < 24 * 400; idx += 256) {
            int l = idx / 400, p = idx - l * 400;
            int py = p / R20, px = p - py * R20;
            int gy = oy0 - 2 + py, gx = ox0 - 2 + px;
            int k = (l < 12) ? (3 * c0 + l) : (3 * c0 + 192 + (l - 12));
            u16 v = 0;   // conv zero-padding outside the image
            if ((unsigned)gy < 256u && (unsigned)gx < 256u)
                v = xcb[(size_t)k * HW + gy * 256 + gx];
            s_xc[l][p] = v;
        }
        __syncthreads();

        // ---- Phase B1a: d3a (grouped 3x3) over 18x18, 2x2 per thread -------
        for (int task = tid; task < 8 * 81; task += 256) {
            int gl = task / 81, patch = task - gl * 81;
            int py = (patch / 9) * 2, px = (patch - (patch / 9) * 9) * 2;
            float bias = s_b3a[gl];
            float a00 = bias, a01 = bias, a10 = bias, a11 = bias;
#pragma unroll
            for (int j = 0; j < 3; ++j) {
                int lc = (gl < 4) ? (3 * gl + j) : (12 + 3 * (gl - 4) + j);
                const u32* base = (const u32*)&s_xc[lc][0];
                float win[4][4];
#pragma unroll
                for (int r = 0; r < 4; ++r) {
                    int e = (py + r) * R20 + px;   // even
                    u32 u0 = base[e >> 1];
                    u32 u1 = base[(e >> 1) + 1];
                    win[r][0] = bflo(u0); win[r][1] = bfhi(u0);
                    win[r][2] = bflo(u1); win[r][3] = bfhi(u1);
                }
#pragma unroll
                for (int ky = 0; ky < 3; ++ky)
#pragma unroll
                    for (int kx = 0; kx < 3; ++kx) {
                        float wgt = s_wd3a[gl][j * 9 + ky * 3 + kx];
                        a00 = fmaf(wgt, win[ky][kx], a00);
                        a01 = fmaf(wgt, win[ky][kx + 1], a01);
                        a10 = fmaf(wgt, win[ky + 1][kx], a10);
                        a11 = fmaf(wgt, win[ky + 1][kx + 1], a11);
                    }
            }
            // zero out-of-image outputs (padding for dwconvIII[1])
            int gy0 = oy0 - 1 + py, gx0 = ox0 - 1 + px;
            bool vy0 = (unsigned)gy0 < 256u, vy1 = (unsigned)(gy0 + 1) < 256u;
            bool vx0 = (unsigned)gx0 < 256u, vx1 = (unsigned)(gx0 + 1) < 256u;
            float* drow = &s_d3a[gl][py * R18 + px];
            drow[0]       = (vy0 && vx0) ? a00 : 0.f;
            drow[1]       = (vy0 && vx1) ? a01 : 0.f;
            drow[R18]     = (vy1 && vx0) ? a10 : 0.f;
            drow[R18 + 1] = (vy1 && vx1) ? a11 : 0.f;
        }

        // ---- Phase B1b: d1 (grouped 3x3) over interior 16x16, 2x2/thread ---
        for (int task = tid; task < 8 * 64; task += 256) {
            int gl = task >> 6, patch = task & 63;
            int py = (patch >> 3) * 2, px = (patch & 7) * 2;
            float bias = s_b1[gl];
            float a00 = bias, a01 = bias, a10 = bias, a11 = bias;
#pragma unroll
            for (int j = 0; j < 3; ++j) {
                int lc = (gl < 4) ? (3 * gl + j) : (12 + 3 * (gl - 4) + j);
                const u32* base = (const u32*)&s_xc[lc][0];
                float win[4][4];
#pragma unroll
                for (int r = 0; r < 4; ++r) {
                    int e = (py + 1 + r) * R20 + px;   // even; cols px+1..px+4
                    u32 u0 = base[e >> 1];
                    u32 u1 = base[(e >> 1) + 1];
                    u32 u2 = base[(e >> 1) + 2];
                    win[r][0] = bfhi(u0); win[r][1] = bflo(u1);
                    win[r][2] = bfhi(u1); win[r][3] = bflo(u2);
                }
#pragma unroll
                for (int ky = 0; ky < 3; ++ky)
#pragma unroll
                    for (int kx = 0; kx < 3; ++kx) {
                        float wgt = s_wd1[gl][j * 9 + ky * 3 + kx];
                        a00 = fmaf(wgt, win[ky][kx], a00);
                        a01 = fmaf(wgt, win[ky][kx + 1], a01);
                        a10 = fmaf(wgt, win[ky + 1][kx], a10);
                        a11 = fmaf(wgt, win[ky + 1][kx + 1], a11);
                    }
            }
            float* drow = &s_d1[gl][py * T + px];
            drow[0] = a00; drow[1] = a01; drow[T] = a10; drow[T + 1] = a11;
        }
        __syncthreads();

        // ---- Phase B2: d3 = depthwise 3x3 over d3a, interior, 2x2/thread ---
        for (int task = tid; task < 8 * 64; task += 256) {
            int gl = task >> 6, patch = task & 63;
            int py = (patch >> 3) * 2, px = (patch & 7) * 2;
            float bias = s_b3b[gl];
            float a00 = bias, a01 = bias, a10 = bias, a11 = bias;
            float win[4][4];
#pragma unroll
            for (int r = 0; r < 4; ++r) {
                int e = (py + r) * R18 + px;
                float2 f0 = *(const float2*)&s_d3a[gl][e];
                float2 f1 = *(const float2*)&s_d3a[gl][e + 2];
                win[r][0] = f0.x; win[r][1] = f0.y;
                win[r][2] = f1.x; win[r][3] = f1.y;
            }
#pragma unroll
            for (int ky = 0; ky < 3; ++ky)
#pragma unroll
                for (int kx = 0; kx < 3; ++kx) {
                    float wgt = s_wd3b[gl][ky * 3 + kx];
                    a00 = fmaf(wgt, win[ky][kx], a00);
                    a01 = fmaf(wgt, win[ky][kx + 1], a01);
                    a10 = fmaf(wgt, win[ky + 1][kx], a10);
                    a11 = fmaf(wgt, win[ky + 1][kx + 1], a11);
                }
            float* drow = &s_d3[gl][py * T + px];
            drow[0] = a00; drow[1] = a01; drow[T] = a10; drow[T + 1] = a11;
        }
        __syncthreads();

        // ---- Phase C: gating + grouped project_out accumulation ------------
#pragma unroll
        for (int jp = 0; jp < 2; ++jp) {
            int j0 = 2 * jp;
            float g1a = gelu_exact(s_d1[j0][tid])     * s_d1[j0 + 4][tid];
            float g1b = gelu_exact(s_d1[j0 + 1][tid]) * s_d1[j0 + 5][tid];
            float g2a = gelu_exact(s_d3[j0][tid])     * s_d3[j0 + 4][tid];
            float g2b = gelu_exact(s_d3[j0 + 1][tid]) * s_d3[j0 + 5][tid];
            int c = c0 + j0;   // even
#pragma unroll
            for (int o = 0; o < 32; ++o) {
                float2 wL = *(const float2*)(w_out + o * 64 + c);
                accL[o] = fmaf(wL.x, g1a, accL[o]);
                accL[o] = fmaf(wL.y, g1b, accL[o]);
                float2 wH = *(const float2*)(w_out + (o + 32) * 64 + c);
                accH[o] = fmaf(wH.x, g2a, accH[o]);
                accH[o] = fmaf(wH.y, g2b, accH[o]);
            }
        }
    }

    // ---- Epilogue: bias + fp32 store --------------------------------------
    {
        int py = tid >> 4, pxx = tid & 15;
        size_t obase = (size_t)b * 64 * HW
                     + (size_t)(oy0 + py) * 256 + (ox0 + pxx);
#pragma unroll
        for (int o = 0; o < 32; ++o) {
            outp[obase + (size_t)o * HW]        = accL[o] + b_out[o];
            outp[obase + (size_t)(o + 32) * HW] = accH[o] + b_out[o + 32];
        }
    }
}

// ---------------------------------------------------------------------------
// Fallback: round-3 fully-fused kernel (used only if ws_size < 201 MB).
// ---------------------------------------------------------------------------
__global__ __launch_bounds__(256, 2)
void ffd_fused(const float* __restrict__ xin, const float* __restrict__ pnin,
               const float* __restrict__ w_in, const float* __restrict__ b_in,
               const float* __restrict__ w_pn, const float* __restrict__ b_pn,
               const float* __restrict__ w_dw1, const float* __restrict__ b_dw1,
               const float* __restrict__ w_dw3a, const float* __restrict__ b_dw3a,
               const float* __restrict__ w_dw3b, const float* __restrict__ b_dw3b,
               const float* __restrict__ w_out, const float* __restrict__ b_out,
               float* __restrict__ outp)
{
    __shared__ __align__(8) u16 s_xc[24][R20 * R20];
    __shared__ __align__(8) float s_d3a[8][R18 * R18];
    __shared__ float s_d1[8][T * T];
    __shared__ float s_d3[8][T * T];
    __shared__ float s_wd1[8][27];
    __shared__ float s_wd3a[8][27];
    __shared__ float s_wd3b[8][9];
    __shared__ float s_b1[8], s_b3a[8], s_b3b[8];

    const int tid = threadIdx.x;
    const int ox0 = blockIdx.x * T;
    const int oy0 = blockIdx.y * T;
    const int b   = blockIdx.z;

    float accL[32], accH[32];
#pragma unroll
    for (int o = 0; o < 32; ++o) { accL[o] = 0.f; accH[o] = 0.f; }

    for (int chunk = 0; chunk < 16; ++chunk) {
        const int c0 = chunk * 4;
        __syncthreads();

        for (int t = tid; t < 512; t += 256) {
            if (t < 216) {
                int gl = t / 27, idx = t - gl * 27;
                int g = (gl < 4) ? (c0 + gl) : (c0 + 60 + gl);
                s_wd1[gl][idx] = w_dw1[g * 27 + idx];
            } else if (t < 432) {
                int t2 = t - 216;
                int gl = t2 / 27, idx = t2 - gl * 27;
                int g = (gl < 4) ? (c0 + gl) : (c0 + 60 + gl);
                s_wd3a[gl][idx] = w_dw3a[g * 27 + idx];
            } else if (t < 504) {
                int t2 = t - 432;
                int gl = t2 / 9, idx = t2 - gl * 9;
                int g = (gl < 4) ? (c0 + gl) : (c0 + 60 + gl);
                s_wd3b[gl][idx] = w_dw3b[g * 9 + idx];
            } else {
                int gl = t - 504;
                int g = (gl < 4) ? (c0 + gl) : (c0 + 60 + gl);
                s_b1[gl]  = b_dw1[g];
                s_b3a[gl] = b_dw3a[g];
                s_b3b[gl] = b_dw3b[g];
            }
        }

        for (int p = tid; p < R20 * R20; p += 256) {
            int py = p / R20, px = p - py * R20;
            int gy = oy0 - 2 + py, gx = ox0 - 2 + px;
            if ((unsigned)gy >= 256u || (unsigned)gx >= 256u) {
#pragma unroll 1
                for (int l = 0; l < 24; ++l) s_xc[l][p] = 0;
                continue;
            }
            const int off = gy * 256 + gx;
            float xr[64];
            const float* xp = xin + (size_t)b * 64 * HW + off;
#pragma unroll
            for (int c = 0; c < 64; ++c) xr[c] = xp[(size_t)c * HW];
            float p0 = 0.f, p1 = 0.f;
            if (3 * c0 < 128) {
                const float* pp = pnin + (size_t)b * 2 * HW + off;
                p0 = pp[0]; p1 = pp[HW];
            }
#pragma unroll 1
            for (int l = 0; l < 24; ++l) {
                int k = (l < 12) ? (3 * c0 + l) : (3 * c0 + 192 + (l - 12));
                float acc;
                if (k < 128) {
                    acc = b_pn[k] + w_pn[2 * k] * p0 + w_pn[2 * k + 1] * p1;
                } else {
                    int kk = k - 128;
                    acc = b_in[kk];
                    const float2* wr = (const float2*)(w_in + kk * 64);
#pragma unroll
                    for (int i = 0; i < 32; ++i) {
                        float2 w2 = wr[i];
                        acc = fmaf(w2.x, xr[2 * i], acc);
                        acc = fmaf(w2.y, xr[2 * i + 1], acc);
                    }
                }
                s_xc[l][p] = f2bf(acc);
            }
        }
        __syncthreads();

        for (int task = tid; task < 8 * 81; task += 256) {
            int gl = task / 81, patch = task - gl * 81;
            int py = (patch / 9) * 2, px = (patch - (patch / 9) * 9) * 2;
            float bias = s_b3a[gl];
            float a00 = bias, a01 = bias, a10 = bias, a11 = bias;
#pragma unroll
            for (int j = 0; j < 3; ++j) {
                int lc = (gl < 4) ? (3 * gl + j) : (12 + 3 * (gl - 4) + j);
                const u32* base = (const u32*)&s_xc[lc][0];
                float win[4][4];
#pragma unroll
                for (int r = 0; r < 4; ++r) {
                    int e = (py + r) * R20 + px;
                    u32 u0 = base[e >> 1];
                    u32 u1 = base[(e >> 1) + 1];
                    win[r][0] = bflo(u0); win[r][1] = bfhi(u0);
                    win[r][2] = bflo(u1); win[r][3] = bfhi(u1);
                }
#pragma unroll
                for (int ky = 0; ky < 3; ++ky)
#pragma unroll
                    for (int kx = 0; kx < 3; ++kx) {
                        float wgt = s_wd3a[gl][j * 9 + ky * 3 + kx];
                        a00 = fmaf(wgt, win[ky][kx], a00);
                        a01 = fmaf(wgt, win[ky][kx + 1], a01);
                        a10 = fmaf(wgt, win[ky + 1][kx], a10);
                        a11 = fmaf(wgt, win[ky + 1][kx + 1], a11);
                    }
            }
            int gy0 = oy0 - 1 + py, gx0 = ox0 - 1 + px;
            bool vy0 = (unsigned)gy0 < 256u, vy1 = (unsigned)(gy0 + 1) < 256u;
            bool vx0 = (unsigned)gx0 < 256u, vx1 = (unsigned)(gx0 + 1) < 256u;
            float* drow = &s_d3a[gl][py * R18 + px];
            drow[0]       = (vy0 && vx0) ? a00 : 0.f;
            drow[1]       = (vy0 && vx1) ? a01 : 0.f;
            drow[R18]     = (vy1 && vx0) ? a10 : 0.f;
            drow[R18 + 1] = (vy1 && vx1) ? a11 : 0.f;
        }

        for (int task = tid; task < 8 * 64; task += 256) {
            int gl = task >> 6, patch = task & 63;
            int py = (patch >> 3) * 2, px = (patch & 7) * 2;
            float bias = s_b1[gl];
            float a00 = bias, a01 = bias, a10 = bias, a11 = bias;
#pragma unroll
            for (int j = 0; j < 3; ++j) {
                int lc = (gl < 4) ? (3 * gl + j) : (12 + 3 * (gl - 4) + j);
                const u32* base = (const u32*)&s_xc[lc][0];
                float win[4][4];
#pragma unroll
                for (int r = 0; r < 4; ++r) {
                    int e = (py + 1 + r) * R20 + px;
                    u32 u0 = base[e >> 1];
                    u32 u1 = base[(e >> 1) + 1];
                    u32 u2 = base[(e >> 1) + 2];
                    win[r][0] = bfhi(u0); win[r][1] = bflo(u1);
                    win[r][2] = bfhi(u1); win[r][3] = bflo(u2);
                }
#pragma unroll
                for (int ky = 0; ky < 3; ++ky)
#pragma unroll
                    for (int kx = 0; kx < 3; ++kx) {
                        float wgt = s_wd1[gl][j * 9 + ky * 3 + kx];
                        a00 = fmaf(wgt, win[ky][kx], a00);
                        a01 = fmaf(wgt, win[ky][kx + 1], a01);
                        a10 = fmaf(wgt, win[ky + 1][kx], a10);
                        a11 = fmaf(wgt, win[ky + 1][kx + 1], a11);
                    }
            }
            float* drow = &s_d1[gl][py * T + px];
            drow[0] = a00; drow[1] = a01; drow[T] = a10; drow[T + 1] = a11;
        }
        __syncthreads();

        for (int task = tid; task < 8 * 64; task += 256) {
            int gl = task >> 6, patch = task & 63;
            int py = (patch >> 3) * 2, px = (patch & 7) * 2;
            float bias = s_b3b[gl];
            float a00 = bias, a01 = bias, a10 = bias, a11 = bias;
            float win[4][4];
#pragma unroll
            for (int r = 0; r < 4; ++r) {
                int e = (py + r) * R18 + px;
                float2 f0 = *(const float2*)&s_d3a[gl][e];
                float2 f1 = *(const float2*)&s_d3a[gl][e + 2];
                win[r][0] = f0.x; win[r][1] = f0.y;
                win[r][2] = f1.x; win[r][3] = f1.y;
            }
#pragma unroll
            for (int ky = 0; ky < 3; ++ky)
#pragma unroll
                for (int kx = 0; kx < 3; ++kx) {
                    float wgt = s_wd3b[gl][ky * 3 + kx];
                    a00 = fmaf(wgt, win[ky][kx], a00);
                    a01 = fmaf(wgt, win[ky][kx + 1], a01);
                    a10 = fmaf(wgt, win[ky + 1][kx], a10);
                    a11 = fmaf(wgt, win[ky + 1][kx + 1], a11);
                }
            float* drow = &s_d3[gl][py * T + px];
            drow[0] = a00; drow[1] = a01; drow[T] = a10; drow[T + 1] = a11;
        }
        __syncthreads();

#pragma unroll
        for (int jp = 0; jp < 2; ++jp) {
            int j0 = 2 * jp;
            float g1a = gelu_exact(s_d1[j0][tid])     * s_d1[j0 + 4][tid];
            float g1b = gelu_exact(s_d1[j0 + 1][tid]) * s_d1[j0 + 5][tid];
            float g2a = gelu_exact(s_d3[j0][tid])     * s_d3[j0 + 4][tid];
            float g2b = gelu_exact(s_d3[j0 + 1][tid]) * s_d3[j0 + 5][tid];
            int c = c0 + j0;
#pragma unroll
            for (int o = 0; o < 32; ++o) {
                float2 wL = *(const float2*)(w_out + o * 64 + c);
                accL[o] = fmaf(wL.x, g1a, accL[o]);
                accL[o] = fmaf(wL.y, g1b, accL[o]);
                float2 wH = *(const float2*)(w_out + (o + 32) * 64 + c);
                accH[o] = fmaf(wH.x, g2a, accH[o]);
                accH[o] = fmaf(wH.y, g2b, accH[o]);
            }
        }
    }

    {
        int py = tid >> 4, pxx = tid & 15;
        size_t obase = (size_t)b * 64 * HW
                     + (size_t)(oy0 + py) * 256 + (ox0 + pxx);
#pragma unroll
        for (int o = 0; o < 32; ++o) {
            outp[obase + (size_t)o * HW]        = accL[o] + b_out[o];
            outp[obase + (size_t)(o + 32) * HW] = accH[o] + b_out[o + 32];
        }
    }
}

extern "C" void kernel_launch(void* const* d_in, const int* in_sizes, int n_in,
                              void* d_out, int out_size, void* d_ws, size_t ws_size,
                              hipStream_t stream) {
    (void)in_sizes; (void)n_in; (void)out_size;
    const float* xin    = (const float*)d_in[0];
    const float* pnin   = (const float*)d_in[1];
    const float* w_in   = (const float*)d_in[2];
    const float* b_in   = (const float*)d_in[3];
    const float* w_pn   = (const float*)d_in[4];
    const float* b_pn   = (const float*)d_in[5];
    const float* w_dw1  = (const float*)d_in[6];
    const float* b_dw1  = (const float*)d_in[7];
    const float* w_dw3a = (const float*)d_in[8];
    const float* b_dw3a = (const float*)d_in[9];
    const float* w_dw3b = (const float*)d_in[10];
    const float* b_dw3b = (const float*)d_in[11];
    const float* w_out  = (const float*)d_in[12];
    const float* b_out  = (const float*)d_in[13];
    float* outp = (float*)d_out;

    if (ws_size >= XC_BYTES) {
        u16* xc = (u16*)d_ws;
        dim3 g1(256, 4), blk(256);
        k1_proj_in<<<g1, blk, 0, stream>>>(xin, pnin, w_in, b_in, w_pn, b_pn, xc);
        dim3 g2(16, 16, 4);
        k2_spatial<<<g2, blk, 0, stream>>>(xc, w_dw1, b_dw1, w_dw3a, b_dw3a,
                                           w_dw3b, b_dw3b, w_out, b_out, outp);
    } else {
        dim3 grid(16, 16, 4), blk(256);
        ffd_fused<<<grid, blk, 0, stream>>>(xin, pnin, w_in, b_in, w_pn, b_pn,
                                            w_dw1, b_dw1, w_dw3a, b_dw3a,
                                            w_dw3b, b_dw3b, w_out, b_out, outp);
    }
}

// Round 5
// 920.081 us; speedup vs baseline: 1.7540x; 1.3261x over previous
//
#include <hip/hip_runtime.h>
#include <hip/hip_bf16.h>

// Two-phase FeedForward_denoise:
//   K1: 1x1 projections (project_in 64->256, project_in_pn 2->128) -> xc bf16
//       in d_ws, layout [B][384][H][W]. One output row at a time so the 64
//       wave-uniform w floats fit in SGPRs (128 live values spilled to VMEM
//       loads in round 4 -> 430 us).
//   K2: per 16x16 tile, load 24 xc channels/chunk from d_ws, grouped 3x3 convs,
//       depthwise 3x3, exact-GELU gating, grouped 1x1 project_out. Intermediate
//       LDS tiles in bf16 -> 35.5 KB LDS -> 4 blocks/CU.
// Fallback to the fully-fused round-3 kernel if ws_size < 201 MB.

#define T 16
#define R20 20
#define R18 18
#define XC_CH 384
#define HW 65536
#define XC_BYTES ((size_t)4 * XC_CH * HW * 2)

typedef unsigned short u16;
typedef unsigned int u32;

__device__ __forceinline__ float bflo(u32 w) {
    union { u32 i; float f; } v; v.i = w << 16; return v.f;
}
__device__ __forceinline__ float bfhi(u32 w) {
    union { u32 i; float f; } v; v.i = w & 0xffff0000u; return v.f;
}
__device__ __forceinline__ float bf2f(u16 u) {
    union { u32 i; float f; } v; v.i = ((u32)u) << 16; return v.f;
}
__device__ __forceinline__ u16 f2bf(float f) {
    union { float f; u32 i; } v; v.f = f;
    u32 x = v.i;
    u32 r = (x + 0x7fffu + ((x >> 16) & 1u)) >> 16;
    return (u16)r;
}
__device__ __forceinline__ float gelu_exact(float v) {
    return 0.5f * v * (1.0f + erff(v * 0.70710678118654752f));
}

// ---------------------------------------------------------------------------
// K1: per-pixel 1x1 projections. One thread = one pixel. w rows are
// wave-uniform; 64 live w floats + 4 accumulator chains keep the weights in
// SGPRs (s_load) and the FMA issue rate at 2 cyc/FMA.
// ---------------------------------------------------------------------------
__global__ __launch_bounds__(256, 4)
void k1_proj_in(const float* __restrict__ xin,   // [4][64][256][256]
                const float* __restrict__ pnin,  // [4][2][256][256]
                const float* __restrict__ w_in,  // [256][64]
                const float* __restrict__ b_in,  // [256]
                const float* __restrict__ w_pn,  // [128][2]
                const float* __restrict__ b_pn,  // [128]
                u16* __restrict__ xc)            // [4][384][256][256] bf16
{
    const int b = blockIdx.y;
    const int p = blockIdx.x * 256 + threadIdx.x;   // 0..65535

    float xr[64];
    const float* xp = xin + (size_t)b * 64 * HW + p;
#pragma unroll
    for (int c = 0; c < 64; ++c) xr[c] = xp[(size_t)c * HW];

    const float p0 = pnin[(size_t)b * 2 * HW + p];
    const float p1 = pnin[(size_t)b * 2 * HW + HW + p];

    u16* xcb = xc + (size_t)b * XC_CH * HW + p;

    // pn part: xc[0..127]
#pragma unroll 8
    for (int i = 0; i < 128; ++i) {
        float acc = fmaf(w_pn[2 * i], p0, fmaf(w_pn[2 * i + 1], p1, b_pn[i]));
        xcb[(size_t)i * HW] = f2bf(acc);
    }
    // xi part: xc[128..383]. One row at a time: 64 uniform w floats live
    // (4 s_load_dwordx16), 4 independent FMA chains.
    for (int j = 0; j < 256; ++j) {
        const float* wr = w_in + j * 64;
        float a0 = 0.f, a1 = 0.f, a2 = 0.f, a3 = 0.f;
#pragma unroll
        for (int c = 0; c < 16; ++c) {
            a0 = fmaf(wr[c],      xr[c],      a0);
            a1 = fmaf(wr[16 + c], xr[16 + c], a1);
            a2 = fmaf(wr[32 + c], xr[32 + c], a2);
            a3 = fmaf(wr[48 + c], xr[48 + c], a3);
        }
        float acc = ((a0 + a1) + (a2 + a3)) + b_in[j];
        xcb[(size_t)(128 + j) * HW] = f2bf(acc);
    }
}

// ---------------------------------------------------------------------------
// K2: spatial convs + gating + project_out, xc streamed from d_ws.
// All LDS intermediates bf16 -> 35.5 KB -> 4 blocks/CU.
// ---------------------------------------------------------------------------
__global__ __launch_bounds__(256, 4)
void k2_spatial(const u16* __restrict__ xc,      // [4][384][256][256] bf16
                const float* __restrict__ w_dw1,  const float* __restrict__ b_dw1,
                const float* __restrict__ w_dw3a, const float* __restrict__ b_dw3a,
                const float* __restrict__ w_dw3b, const float* __restrict__ b_dw3b,
                const float* __restrict__ w_out,  const float* __restrict__ b_out,
                float* __restrict__ outp)         // [4][64][256][256]
{
    __shared__ __align__(8) u16 s_xc[24][R20 * R20];
    __shared__ __align__(8) u16 s_d3a[8][R18 * R18];   // bf16
    __shared__ __align__(8) u16 s_d1[8][T * T];        // bf16
    __shared__ __align__(8) u16 s_d3[8][T * T];        // bf16
    __shared__ float s_wd1[8][27];
    __shared__ float s_wd3a[8][27];
    __shared__ float s_wd3b[8][9];
    __shared__ float s_b1[8], s_b3a[8], s_b3b[8];

    const int tid = threadIdx.x;
    const int ox0 = blockIdx.x * T;
    const int oy0 = blockIdx.y * T;
    const int b   = blockIdx.z;

    const u16* xcb = xc + (size_t)b * XC_CH * HW;

    float accL[32], accH[32];
#pragma unroll
    for (int o = 0; o < 32; ++o) { accL[o] = 0.f; accH[o] = 0.f; }

    for (int chunk = 0; chunk < 16; ++chunk) {
        const int c0 = chunk * 4;
        __syncthreads();   // protect s_* reuse across chunks

        // ---- Phase W: stage chunk weights into LDS -------------------------
        for (int t = tid; t < 512; t += 256) {
            if (t < 216) {
                int gl = t / 27, idx = t - gl * 27;
                int g = (gl < 4) ? (c0 + gl) : (c0 + 60 + gl);
                s_wd1[gl][idx] = w_dw1[g * 27 + idx];
            } else if (t < 432) {
                int t2 = t - 216;
                int gl = t2 / 27, idx = t2 - gl * 27;
                int g = (gl < 4) ? (c0 + gl) : (c0 + 60 + gl);
                s_wd3a[gl][idx] = w_dw3a[g * 27 + idx];
            } else if (t < 504) {
                int t2 = t - 432;
                int gl = t2 / 9, idx = t2 - gl * 9;
                int g = (gl < 4) ? (c0 + gl) : (c0 + 60 + gl);
                s_wd3b[gl][idx] = w_dw3b[g * 9 + idx];
            } else {
                int gl = t - 504;
                int g = (gl < 4) ? (c0 + gl) : (c0 + 60 + gl);
                s_b1[gl]  = b_dw1[g];
                s_b3a[gl] = b_dw3a[g];
                s_b3b[gl] = b_dw3b[g];
            }
        }

        // ---- Phase A: load chunk's 24 xc channels over 20x20 halo ----------
        for (int idx = tid; idx < 24 * 400; idx += 256) {
            int l = idx / 400, p = idx - l * 400;
            int py = p / R20, px = p - py * R20;
            int gy = oy0 - 2 + py, gx = ox0 - 2 + px;
            int k = (l < 12) ? (3 * c0 + l) : (3 * c0 + 192 + (l - 12));
            u16 v = 0;   // conv zero-padding outside the image
            if ((unsigned)gy < 256u && (unsigned)gx < 256u)
                v = xcb[(size_t)k * HW + gy * 256 + gx];
            s_xc[l][p] = v;
        }
        __syncthreads();

        // ---- Phase B1a: d3a (grouped 3x3) over 18x18, 2x2 per thread -------
        for (int task = tid; task < 8 * 81; task += 256) {
            int gl = task / 81, patch = task - gl * 81;
            int py = (patch / 9) * 2, px = (patch - (patch / 9) * 9) * 2;
            float bias = s_b3a[gl];
            float a00 = bias, a01 = bias, a10 = bias, a11 = bias;
#pragma unroll
            for (int j = 0; j < 3; ++j) {
                int lc = (gl < 4) ? (3 * gl + j) : (12 + 3 * (gl - 4) + j);
                const u32* base = (const u32*)&s_xc[lc][0];
                float win[4][4];
#pragma unroll
                for (int r = 0; r < 4; ++r) {
                    int e = (py + r) * R20 + px;   // even
                    u32 u0 = base[e >> 1];
                    u32 u1 = base[(e >> 1) + 1];
                    win[r][0] = bflo(u0); win[r][1] = bfhi(u0);
                    win[r][2] = bflo(u1); win[r][3] = bfhi(u1);
                }
#pragma unroll
                for (int ky = 0; ky < 3; ++ky)
#pragma unroll
                    for (int kx = 0; kx < 3; ++kx) {
                        float wgt = s_wd3a[gl][j * 9 + ky * 3 + kx];
                        a00 = fmaf(wgt, win[ky][kx], a00);
                        a01 = fmaf(wgt, win[ky][kx + 1], a01);
                        a10 = fmaf(wgt, win[ky + 1][kx], a10);
                        a11 = fmaf(wgt, win[ky + 1][kx + 1], a11);
                    }
            }
            // zero out-of-image outputs (padding for dwconvIII[1])
            int gy0 = oy0 - 1 + py, gx0 = ox0 - 1 + px;
            bool vy0 = (unsigned)gy0 < 256u, vy1 = (unsigned)(gy0 + 1) < 256u;
            bool vx0 = (unsigned)gx0 < 256u, vx1 = (unsigned)(gx0 + 1) < 256u;
            u16* drow = &s_d3a[gl][py * R18 + px];
            drow[0]       = (vy0 && vx0) ? f2bf(a00) : (u16)0;
            drow[1]       = (vy0 && vx1) ? f2bf(a01) : (u16)0;
            drow[R18]     = (vy1 && vx0) ? f2bf(a10) : (u16)0;
            drow[R18 + 1] = (vy1 && vx1) ? f2bf(a11) : (u16)0;
        }

        // ---- Phase B1b: d1 (grouped 3x3) over interior 16x16, 2x2/thread ---
        for (int task = tid; task < 8 * 64; task += 256) {
            int gl = task >> 6, patch = task & 63;
            int py = (patch >> 3) * 2, px = (patch & 7) * 2;
            float bias = s_b1[gl];
            float a00 = bias, a01 = bias, a10 = bias, a11 = bias;
#pragma unroll
            for (int j = 0; j < 3; ++j) {
                int lc = (gl < 4) ? (3 * gl + j) : (12 + 3 * (gl - 4) + j);
                const u32* base = (const u32*)&s_xc[lc][0];
                float win[4][4];
#pragma unroll
                for (int r = 0; r < 4; ++r) {
                    int e = (py + 1 + r) * R20 + px;   // even; cols px+1..px+4
                    u32 u0 = base[e >> 1];
                    u32 u1 = base[(e >> 1) + 1];
                    u32 u2 = base[(e >> 1) + 2];
                    win[r][0] = bfhi(u0); win[r][1] = bflo(u1);
                    win[r][2] = bfhi(u1); win[r][3] = bflo(u2);
                }
#pragma unroll
                for (int ky = 0; ky < 3; ++ky)
#pragma unroll
                    for (int kx = 0; kx < 3; ++kx) {
                        float wgt = s_wd1[gl][j * 9 + ky * 3 + kx];
                        a00 = fmaf(wgt, win[ky][kx], a00);
                        a01 = fmaf(wgt, win[ky][kx + 1], a01);
                        a10 = fmaf(wgt, win[ky + 1][kx], a10);
                        a11 = fmaf(wgt, win[ky + 1][kx + 1], a11);
                    }
            }
            u16* drow = &s_d1[gl][py * T + px];
            drow[0] = f2bf(a00); drow[1] = f2bf(a01);
            drow[T] = f2bf(a10); drow[T + 1] = f2bf(a11);
        }
        __syncthreads();

        // ---- Phase B2: d3 = depthwise 3x3 over d3a, interior, 2x2/thread ---
        for (int task = tid; task < 8 * 64; task += 256) {
            int gl = task >> 6, patch = task & 63;
            int py = (patch >> 3) * 2, px = (patch & 7) * 2;
            float bias = s_b3b[gl];
            float a00 = bias, a01 = bias, a10 = bias, a11 = bias;
            float win[4][4];
            const u32* base = (const u32*)&s_d3a[gl][0];
#pragma unroll
            for (int r = 0; r < 4; ++r) {
                int e = (py + r) * R18 + px;   // even (R18 even, px even)
                u32 u0 = base[e >> 1];
                u32 u1 = base[(e >> 1) + 1];
                win[r][0] = bflo(u0); win[r][1] = bfhi(u0);
                win[r][2] = bflo(u1); win[r][3] = bfhi(u1);
            }
#pragma unroll
            for (int ky = 0; ky < 3; ++ky)
#pragma unroll
                for (int kx = 0; kx < 3; ++kx) {
                    float wgt = s_wd3b[gl][ky * 3 + kx];
                    a00 = fmaf(wgt, win[ky][kx], a00);
                    a01 = fmaf(wgt, win[ky][kx + 1], a01);
                    a10 = fmaf(wgt, win[ky + 1][kx], a10);
                    a11 = fmaf(wgt, win[ky + 1][kx + 1], a11);
                }
            u16* drow = &s_d3[gl][py * T + px];
            drow[0] = f2bf(a00); drow[1] = f2bf(a01);
            drow[T] = f2bf(a10); drow[T + 1] = f2bf(a11);
        }
        __syncthreads();

        // ---- Phase C: gating + grouped project_out accumulation ------------
#pragma unroll
        for (int jp = 0; jp < 2; ++jp) {
            int j0 = 2 * jp;
            float g1a = gelu_exact(bf2f(s_d1[j0][tid]))     * bf2f(s_d1[j0 + 4][tid]);
            float g1b = gelu_exact(bf2f(s_d1[j0 + 1][tid])) * bf2f(s_d1[j0 + 5][tid]);
            float g2a = gelu_exact(bf2f(s_d3[j0][tid]))     * bf2f(s_d3[j0 + 4][tid]);
            float g2b = gelu_exact(bf2f(s_d3[j0 + 1][tid])) * bf2f(s_d3[j0 + 5][tid]);
            int c = c0 + j0;   // even
#pragma unroll
            for (int o = 0; o < 32; ++o) {
                float2 wL = *(const float2*)(w_out + o * 64 + c);
                accL[o] = fmaf(wL.x, g1a, accL[o]);
                accL[o] = fmaf(wL.y, g1b, accL[o]);
                float2 wH = *(const float2*)(w_out + (o + 32) * 64 + c);
                accH[o] = fmaf(wH.x, g2a, accH[o]);
                accH[o] = fmaf(wH.y, g2b, accH[o]);
            }
        }
    }

    // ---- Epilogue: bias + fp32 store --------------------------------------
    {
        int py = tid >> 4, pxx = tid & 15;
        size_t obase = (size_t)b * 64 * HW
                     + (size_t)(oy0 + py) * 256 + (ox0 + pxx);
#pragma unroll
        for (int o = 0; o < 32; ++o) {
            outp[obase + (size_t)o * HW]        = accL[o] + b_out[o];
            outp[obase + (size_t)(o + 32) * HW] = accH[o] + b_out[o + 32];
        }
    }
}

// ---------------------------------------------------------------------------
// Fallback: round-3 fully-fused kernel (used only if ws_size < 201 MB).
// ---------------------------------------------------------------------------
__global__ __launch_bounds__(256, 2)
void ffd_fused(const float* __restrict__ xin, const float* __restrict__ pnin,
               const float* __restrict__ w_in, const float* __restrict__ b_in,
               const float* __restrict__ w_pn, const float* __restrict__ b_pn,
               const float* __restrict__ w_dw1, const float* __restrict__ b_dw1,
               const float* __restrict__ w_dw3a, const float* __restrict__ b_dw3a,
               const float* __restrict__ w_dw3b, const float* __restrict__ b_dw3b,
               const float* __restrict__ w_out, const float* __restrict__ b_out,
               float* __restrict__ outp)
{
    __shared__ __align__(8) u16 s_xc[24][R20 * R20];
    __shared__ __align__(8) float s_d3a[8][R18 * R18];
    __shared__ float s_d1[8][T * T];
    __shared__ float s_d3[8][T * T];
    __shared__ float s_wd1[8][27];
    __shared__ float s_wd3a[8][27];
    __shared__ float s_wd3b[8][9];
    __shared__ float s_b1[8], s_b3a[8], s_b3b[8];

    const int tid = threadIdx.x;
    const int ox0 = blockIdx.x * T;
    const int oy0 = blockIdx.y * T;
    const int b   = blockIdx.z;

    float accL[32], accH[32];
#pragma unroll
    for (int o = 0; o < 32; ++o) { accL[o] = 0.f; accH[o] = 0.f; }

    for (int chunk = 0; chunk < 16; ++chunk) {
        const int c0 = chunk * 4;
        __syncthreads();

        for (int t = tid; t < 512; t += 256) {
            if (t < 216) {
                int gl = t / 27, idx = t - gl * 27;
                int g = (gl < 4) ? (c0 + gl) : (c0 + 60 + gl);
                s_wd1[gl][idx] = w_dw1[g * 27 + idx];
            } else if (t < 432) {
                int t2 = t - 216;
                int gl = t2 / 27, idx = t2 - gl * 27;
                int g = (gl < 4) ? (c0 + gl) : (c0 + 60 + gl);
                s_wd3a[gl][idx] = w_dw3a[g * 27 + idx];
            } else if (t < 504) {
                int t2 = t - 432;
                int gl = t2 / 9, idx = t2 - gl * 9;
                int g = (gl < 4) ? (c0 + gl) : (c0 + 60 + gl);
                s_wd3b[gl][idx] = w_dw3b[g * 9 + idx];
            } else {
                int gl = t - 504;
                int g = (gl < 4) ? (c0 + gl) : (c0 + 60 + gl);
                s_b1[gl]  = b_dw1[g];
                s_b3a[gl] = b_dw3a[g];
                s_b3b[gl] = b_dw3b[g];
            }
        }

        for (int p = tid; p < R20 * R20; p += 256) {
            int py = p / R20, px = p - py * R20;
            int gy = oy0 - 2 + py, gx = ox0 - 2 + px;
            if ((unsigned)gy >= 256u || (unsigned)gx >= 256u) {
#pragma unroll 1
                for (int l = 0; l < 24; ++l) s_xc[l][p] = 0;
                continue;
            }
            const int off = gy * 256 + gx;
            float xr[64];
            const float* xp = xin + (size_t)b * 64 * HW + off;
#pragma unroll
            for (int c = 0; c < 64; ++c) xr[c] = xp[(size_t)c * HW];
            float p0 = 0.f, p1 = 0.f;
            if (3 * c0 < 128) {
                const float* pp = pnin + (size_t)b * 2 * HW + off;
                p0 = pp[0]; p1 = pp[HW];
            }
#pragma unroll 1
            for (int l = 0; l < 24; ++l) {
                int k = (l < 12) ? (3 * c0 + l) : (3 * c0 + 192 + (l - 12));
                float acc;
                if (k < 128) {
                    acc = b_pn[k] + w_pn[2 * k] * p0 + w_pn[2 * k + 1] * p1;
                } else {
                    int kk = k - 128;
                    acc = b_in[kk];
                    const float2* wr = (const float2*)(w_in + kk * 64);
#pragma unroll
                    for (int i = 0; i < 32; ++i) {
                        float2 w2 = wr[i];
                        acc = fmaf(w2.x, xr[2 * i], acc);
                        acc = fmaf(w2.y, xr[2 * i + 1], acc);
                    }
                }
                s_xc[l][p] = f2bf(acc);
            }
        }
        __syncthreads();

        for (int task = tid; task < 8 * 81; task += 256) {
            int gl = task / 81, patch = task - gl * 81;
            int py = (patch / 9) * 2, px = (patch - (patch / 9) * 9) * 2;
            float bias = s_b3a[gl];
            float a00 = bias, a01 = bias, a10 = bias, a11 = bias;
#pragma unroll
            for (int j = 0; j < 3; ++j) {
                int lc = (gl < 4) ? (3 * gl + j) : (12 + 3 * (gl - 4) + j);
                const u32* base = (const u32*)&s_xc[lc][0];
                float win[4][4];
#pragma unroll
                for (int r = 0; r < 4; ++r) {
                    int e = (py + r) * R20 + px;
                    u32 u0 = base[e >> 1];
                    u32 u1 = base[(e >> 1) + 1];
                    win[r][0] = bflo(u0); win[r][1] = bfhi(u0);
                    win[r][2] = bflo(u1); win[r][3] = bfhi(u1);
                }
#pragma unroll
                for (int ky = 0; ky < 3; ++ky)
#pragma unroll
                    for (int kx = 0; kx < 3; ++kx) {
                        float wgt = s_wd3a[gl][j * 9 + ky * 3 + kx];
                        a00 = fmaf(wgt, win[ky][kx], a00);
                        a01 = fmaf(wgt, win[ky][kx + 1], a01);
                        a10 = fmaf(wgt, win[ky + 1][kx], a10);
                        a11 = fmaf(wgt, win[ky + 1][kx + 1], a11);
                    }
            }
            int gy0 = oy0 - 1 + py, gx0 = ox0 - 1 + px;
            bool vy0 = (unsigned)gy0 < 256u, vy1 = (unsigned)(gy0 + 1) < 256u;
            bool vx0 = (unsigned)gx0 < 256u, vx1 = (unsigned)(gx0 + 1) < 256u;
            float* drow = &s_d3a[gl][py * R18 + px];
            drow[0]       = (vy0 && vx0) ? a00 : 0.f;
            drow[1]       = (vy0 && vx1) ? a01 : 0.f;
            drow[R18]     = (vy1 && vx0) ? a10 : 0.f;
            drow[R18 + 1] = (vy1 && vx1) ? a11 : 0.f;
        }

        for (int task = tid; task < 8 * 64; task += 256) {
            int gl = task >> 6, patch = task & 63;
            int py = (patch >> 3) * 2, px = (patch & 7) * 2;
            float bias = s_b1[gl];
            float a00 = bias, a01 = bias, a10 = bias, a11 = bias;
#pragma unroll
            for (int j = 0; j < 3; ++j) {
                int lc = (gl < 4) ? (3 * gl + j) : (12 + 3 * (gl - 4) + j);
                const u32* base = (const u32*)&s_xc[lc][0];
                float win[4][4];
#pragma unroll
                for (int r = 0; r < 4; ++r) {
                    int e = (py + 1 + r) * R20 + px;
                    u32 u0 = base[e >> 1];
                    u32 u1 = base[(e >> 1) + 1];
                    u32 u2 = base[(e >> 1) + 2];
                    win[r][0] = bfhi(u0); win[r][1] = bflo(u1);
                    win[r][2] = bfhi(u1); win[r][3] = bflo(u2);
                }
#pragma unroll
                for (int ky = 0; ky < 3; ++ky)
#pragma unroll
                    for (int kx = 0; kx < 3; ++kx) {
                        float wgt = s_wd1[gl][j * 9 + ky * 3 + kx];
                        a00 = fmaf(wgt, win[ky][kx], a00);
                        a01 = fmaf(wgt, win[ky][kx + 1], a01);
                        a10 = fmaf(wgt, win[ky + 1][kx], a10);
                        a11 = fmaf(wgt, win[ky + 1][kx + 1], a11);
                    }
            }
            float* drow = &s_d1[gl][py * T + px];
            drow[0] = a00; drow[1] = a01; drow[T] = a10; drow[T + 1] = a11;
        }
        __syncthreads();

        for (int task = tid; task < 8 * 64; task += 256) {
            int gl = task >> 6, patch = task & 63;
            int py = (patch >> 3) * 2, px = (patch & 7) * 2;
            float bias = s_b3b[gl];
            float a00 = bias, a01 = bias, a10 = bias, a11 = bias;
            float win[4][4];
#pragma unroll
            for (int r = 0; r < 4; ++r) {
                int e = (py + r) * R18 + px;
                float2 f0 = *(const float2*)&s_d3a[gl][e];
                float2 f1 = *(const float2*)&s_d3a[gl][e + 2];
                win[r][0] = f0.x; win[r][1] = f0.y;
                win[r][2] = f1.x; win[r][3] = f1.y;
            }
#pragma unroll
            for (int ky = 0; ky < 3; ++ky)
#pragma unroll
                for (int kx = 0; kx < 3; ++kx) {
                    float wgt = s_wd3b[gl][ky * 3 + kx];
                    a00 = fmaf(wgt, win[ky][kx], a00);
                    a01 = fmaf(wgt, win[ky][kx + 1], a01);
                    a10 = fmaf(wgt, win[ky + 1][kx], a10);
                    a11 = fmaf(wgt, win[ky + 1][kx + 1], a11);
                }
            float* drow = &s_d3[gl][py * T + px];
            drow[0] = a00; drow[1] = a01; drow[T] = a10; drow[T + 1] = a11;
        }
        __syncthreads();

#pragma unroll
        for (int jp = 0; jp < 2; ++jp) {
            int j0 = 2 * jp;
            float g1a = gelu_exact(s_d1[j0][tid])     * s_d1[j0 + 4][tid];
            float g1b = gelu_exact(s_d1[j0 + 1][tid]) * s_d1[j0 + 5][tid];
            float g2a = gelu_exact(s_d3[j0][tid])     * s_d3[j0 + 4][tid];
            float g2b = gelu_exact(s_d3[j0 + 1][tid]) * s_d3[j0 + 5][tid];
            int c = c0 + j0;
#pragma unroll
            for (int o = 0; o < 32; ++o) {
                float2 wL = *(const float2*)(w_out + o * 64 + c);
                accL[o] = fmaf(wL.x, g1a, accL[o]);
                accL[o] = fmaf(wL.y, g1b, accL[o]);
                float2 wH = *(const float2*)(w_out + (o + 32) * 64 + c);
                accH[o] = fmaf(wH.x, g2a, accH[o]);
                accH[o] = fmaf(wH.y, g2b, accH[o]);
            }
        }
    }

    {
        int py = tid >> 4, pxx = tid & 15;
        size_t obase = (size_t)b * 64 * HW
                     + (size_t)(oy0 + py) * 256 + (ox0 + pxx);
#pragma unroll
        for (int o = 0; o < 32; ++o) {
            outp[obase + (size_t)o * HW]        = accL[o] + b_out[o];
            outp[obase + (size_t)(o + 32) * HW] = accH[o] + b_out[o + 32];
        }
    }
}

extern "C" void kernel_launch(void* const* d_in, const int* in_sizes, int n_in,
                              void* d_out, int out_size, void* d_ws, size_t ws_size,
                              hipStream_t stream) {
    (void)in_sizes; (void)n_in; (void)out_size;
    const float* xin    = (const float*)d_in[0];
    const float* pnin   = (const float*)d_in[1];
    const float* w_in   = (const float*)d_in[2];
    const float* b_in   = (const float*)d_in[3];
    const float* w_pn   = (const float*)d_in[4];
    const float* b_pn   = (const float*)d_in[5];
    const float* w_dw1  = (const float*)d_in[6];
    const float* b_dw1  = (const float*)d_in[7];
    const float* w_dw3a = (const float*)d_in[8];
    const float* b_dw3a = (const float*)d_in[9];
    const float* w_dw3b = (const float*)d_in[10];
    const float* b_dw3b = (const float*)d_in[11];
    const float* w_out  = (const float*)d_in[12];
    const float* b_out  = (const float*)d_in[13];
    float* outp = (float*)d_out;

    if (ws_size >= XC_BYTES) {
        u16* xc = (u16*)d_ws;
        dim3 g1(256, 4), blk(256);
        k1_proj_in<<<g1, blk, 0, stream>>>(xin, pnin, w_in, b_in, w_pn, b_pn, xc);
        dim3 g2(16, 16, 4);
        k2_spatial<<<g2, blk, 0, stream>>>(xc, w_dw1, b_dw1, w_dw3a, b_dw3a,
                                           w_dw3b, b_dw3b, w_out, b_out, outp);
    } else {
        dim3 grid(16, 16, 4), blk(256);
        ffd_fused<<<grid, blk, 0, stream>>>(xin, pnin, w_in, b_in, w_pn, b_pn,
                                            w_dw1, b_dw1, w_dw3a, b_dw3a,
                                            w_dw3b, b_dw3b, w_out, b_out, outp);
    }
}

// Round 6
// 829.868 us; speedup vs baseline: 1.9447x; 1.1087x over previous
//
#include <hip/hip_runtime.h>
#include <hip/hip_bf16.h>

// Two-phase FeedForward_denoise:
//   K1: 1x1 projections -> xc bf16 in d_ws, layout [B][16 chunks][HW][24 ch]
//       (chunk-pixel-major: K2's halo reads become 3 aligned dwordx4/pixel).
//       w_in staged in LDS (64 KB) -> broadcast reads, FMA-issue bound.
//   K2: 512 threads/block, 16x16 tile. Per chunk: load 24 xc ch over 20x20
//       halo, grouped 3x3 convs, depthwise 3x3, GELU gating, grouped 1x1
//       project_out with per-half 32 accumulators (no spills; r5's 64 accs
//       under a 64-VGPR cap spilled to scratch -> +770 MB HBM traffic).
// Fallback to the fully-fused round-3 kernel if ws_size < 201 MB.

#define T 16
#define R20 20
#define R18 18
#define HW 65536
#define XC_BYTES ((size_t)4 * 16 * HW * 24 * 2)

typedef unsigned short u16;
typedef unsigned int u32;

__device__ __forceinline__ float bflo(u32 w) {
    union { u32 i; float f; } v; v.i = w << 16; return v.f;
}
__device__ __forceinline__ float bfhi(u32 w) {
    union { u32 i; float f; } v; v.i = w & 0xffff0000u; return v.f;
}
__device__ __forceinline__ float bf2f(u16 u) {
    union { u32 i; float f; } v; v.i = ((u32)u) << 16; return v.f;
}
__device__ __forceinline__ u16 f2bf(float f) {
    union { float f; u32 i; } v; v.f = f;
    u32 x = v.i;
    u32 r = (x + 0x7fffu + ((x >> 16) & 1u)) >> 16;
    return (u16)r;
}
__device__ __forceinline__ float gelu_exact(float v) {
    return 0.5f * v * (1.0f + erff(v * 0.70710678118654752f));
}

// ---------------------------------------------------------------------------
// K1: per-pixel 1x1 projections, chunk-pixel-major bf16 output.
// ---------------------------------------------------------------------------
__global__ __launch_bounds__(256, 2)
void k1_proj_in(const float* __restrict__ xin,   // [4][64][256][256]
                const float* __restrict__ pnin,  // [4][2][256][256]
                const float* __restrict__ w_in,  // [256][64]
                const float* __restrict__ b_in,  // [256]
                const float* __restrict__ w_pn,  // [128][2]
                const float* __restrict__ b_pn,  // [128]
                u16* __restrict__ xc)            // [4][16][HW][24] bf16
{
    __shared__ float s_w[256 * 64];   // 64 KB
    __shared__ float s_wpn[256];
    __shared__ float s_bpn[128];
    __shared__ float s_bin[256];

    const int tid = threadIdx.x;

    // stage weights
    for (int i = tid; i < 256 * 16; i += 256)          // float4 elements
        ((float4*)s_w)[i] = ((const float4*)w_in)[i];
    s_wpn[tid] = w_pn[tid];
    s_bin[tid] = b_in[tid];
    if (tid < 128) s_bpn[tid] = b_pn[tid];
    __syncthreads();

    const int b = blockIdx.y;
    const int p = blockIdx.x * 256 + tid;   // 0..65535

    float xr[64];
    const float* xp = xin + (size_t)b * 64 * HW + p;
#pragma unroll
    for (int c = 0; c < 64; ++c) xr[c] = xp[(size_t)c * HW];

    const float p0 = pnin[(size_t)b * 2 * HW + p];
    const float p1 = pnin[(size_t)b * 2 * HW + HW + p];

#pragma unroll 1
    for (int chunk = 0; chunk < 16; ++chunk) {
        const int c0 = chunk * 4;
        union { uint4 q[3]; u16 h[24]; } ov;
#pragma unroll 1
        for (int l = 0; l < 24; ++l) {
            int k = (l < 12) ? (3 * c0 + l) : (3 * c0 + 192 + (l - 12));
            float acc;
            if (k < 128) {
                acc = fmaf(s_wpn[2 * k], p0,
                      fmaf(s_wpn[2 * k + 1], p1, s_bpn[k]));
            } else {
                const float* wr = s_w + (k - 128) * 64;
                float a0 = 0.f, a1 = 0.f, a2 = 0.f, a3 = 0.f;
#pragma unroll
                for (int c = 0; c < 16; ++c) {
                    a0 = fmaf(wr[c],      xr[c],      a0);
                    a1 = fmaf(wr[16 + c], xr[16 + c], a1);
                    a2 = fmaf(wr[32 + c], xr[32 + c], a2);
                    a3 = fmaf(wr[48 + c], xr[48 + c], a3);
                }
                acc = ((a0 + a1) + (a2 + a3)) + s_bin[k - 128];
            }
            ov.h[l] = f2bf(acc);
        }
        uint4* dst = (uint4*)(xc + ((size_t)(b * 16 + chunk) * HW + p) * 24);
        dst[0] = ov.q[0]; dst[1] = ov.q[1]; dst[2] = ov.q[2];
    }
}

// ---------------------------------------------------------------------------
// K2: spatial convs + gating + project_out. 512 threads, split-half epilogue.
// ---------------------------------------------------------------------------
__global__ __launch_bounds__(512, 4)
void k2_spatial(const u16* __restrict__ xc,       // [4][16][HW][24] bf16
                const float* __restrict__ w_dw1,  const float* __restrict__ b_dw1,
                const float* __restrict__ w_dw3a, const float* __restrict__ b_dw3a,
                const float* __restrict__ w_dw3b, const float* __restrict__ b_dw3b,
                const float* __restrict__ w_out,  const float* __restrict__ b_out,
                float* __restrict__ outp)         // [4][64][256][256]
{
    __shared__ __align__(8) u16 s_xc[24][R20 * R20];
    __shared__ __align__(8) u16 s_d3a[8][R18 * R18];
    __shared__ __align__(8) u16 s_d1[8][T * T];
    __shared__ __align__(8) u16 s_d3[8][T * T];
    __shared__ float s_wout[64 * 64];   // 16 KB fp32
    __shared__ float s_wd1[8][27];
    __shared__ float s_wd3a[8][27];
    __shared__ float s_wd3b[8][9];
    __shared__ float s_b1[8], s_b3a[8], s_b3b[8];

    const int tid  = threadIdx.x;
    const int half = tid >> 8;          // wave-uniform (waves 0-3 vs 4-7)
    const int pix  = tid & 255;
    const int ox0 = blockIdx.x * T;
    const int oy0 = blockIdx.y * T;
    const int b   = blockIdx.z;

    // stage w_out once (consumed after the first loop-top barrier)
    for (int i = tid; i < 4096; i += 512) s_wout[i] = w_out[i];

    float acc[32];
#pragma unroll
    for (int o = 0; o < 32; ++o) acc[o] = 0.f;

    for (int chunk = 0; chunk < 16; ++chunk) {
        const int c0 = chunk * 4;
        __syncthreads();   // protect s_* reuse across chunks (+ w_out 1st iter)

        // ---- Phase W: stage chunk weights into LDS -------------------------
        if (tid < 512) {
            int t = tid;
            if (t < 216) {
                int gl = t / 27, idx = t - gl * 27;
                int g = (gl < 4) ? (c0 + gl) : (c0 + 60 + gl);
                s_wd1[gl][idx] = w_dw1[g * 27 + idx];
            } else if (t < 432) {
                int t2 = t - 216;
                int gl = t2 / 27, idx = t2 - gl * 27;
                int g = (gl < 4) ? (c0 + gl) : (c0 + 60 + gl);
                s_wd3a[gl][idx] = w_dw3a[g * 27 + idx];
            } else if (t < 504) {
                int t2 = t - 432;
                int gl = t2 / 9, idx = t2 - gl * 9;
                int g = (gl < 4) ? (c0 + gl) : (c0 + 60 + gl);
                s_wd3b[gl][idx] = w_dw3b[g * 9 + idx];
            } else {
                int gl = t - 504;
                int g = (gl < 4) ? (c0 + gl) : (c0 + 60 + gl);
                s_b1[gl]  = b_dw1[g];
                s_b3a[gl] = b_dw3a[g];
                s_b3b[gl] = b_dw3b[g];
            }
        }

        // ---- Phase A: 24 xc channels over 20x20 halo (3 dwordx4 / pixel) ---
        if (tid < 400) {
            int py = tid / R20, px = tid - py * R20;
            int gy = oy0 - 2 + py, gx = ox0 - 2 + px;
            union { uint4 q[3]; u16 h[24]; } v;
            if ((unsigned)gy < 256u && (unsigned)gx < 256u) {
                const uint4* src = (const uint4*)(xc +
                    ((size_t)(b * 16 + chunk) * HW + gy * 256 + gx) * 24);
                v.q[0] = src[0]; v.q[1] = src[1]; v.q[2] = src[2];
            } else {
                v.q[0] = make_uint4(0, 0, 0, 0);
                v.q[1] = make_uint4(0, 0, 0, 0);
                v.q[2] = make_uint4(0, 0, 0, 0);
            }
#pragma unroll
            for (int l = 0; l < 24; ++l) s_xc[l][tid] = v.h[l];
        }
        __syncthreads();

        // ---- Phase B1a: d3a (grouped 3x3) over 18x18, 2x2 per thread -------
        for (int task = tid; task < 8 * 81; task += 512) {
            int gl = task / 81, patch = task - gl * 81;
            int py = (patch / 9) * 2, px = (patch - (patch / 9) * 9) * 2;
            float bias = s_b3a[gl];
            float a00 = bias, a01 = bias, a10 = bias, a11 = bias;
#pragma unroll
            for (int j = 0; j < 3; ++j) {
                int lc = (gl < 4) ? (3 * gl + j) : (12 + 3 * (gl - 4) + j);
                const u32* base = (const u32*)&s_xc[lc][0];
                float win[4][4];
#pragma unroll
                for (int r = 0; r < 4; ++r) {
                    int e = (py + r) * R20 + px;   // even
                    u32 u0 = base[e >> 1];
                    u32 u1 = base[(e >> 1) + 1];
                    win[r][0] = bflo(u0); win[r][1] = bfhi(u0);
                    win[r][2] = bflo(u1); win[r][3] = bfhi(u1);
                }
#pragma unroll
                for (int ky = 0; ky < 3; ++ky)
#pragma unroll
                    for (int kx = 0; kx < 3; ++kx) {
                        float wgt = s_wd3a[gl][j * 9 + ky * 3 + kx];
                        a00 = fmaf(wgt, win[ky][kx], a00);
                        a01 = fmaf(wgt, win[ky][kx + 1], a01);
                        a10 = fmaf(wgt, win[ky + 1][kx], a10);
                        a11 = fmaf(wgt, win[ky + 1][kx + 1], a11);
                    }
            }
            int gy0 = oy0 - 1 + py, gx0 = ox0 - 1 + px;
            bool vy0 = (unsigned)gy0 < 256u, vy1 = (unsigned)(gy0 + 1) < 256u;
            bool vx0 = (unsigned)gx0 < 256u, vx1 = (unsigned)(gx0 + 1) < 256u;
            u16* drow = &s_d3a[gl][py * R18 + px];
            drow[0]       = (vy0 && vx0) ? f2bf(a00) : (u16)0;
            drow[1]       = (vy0 && vx1) ? f2bf(a01) : (u16)0;
            drow[R18]     = (vy1 && vx0) ? f2bf(a10) : (u16)0;
            drow[R18 + 1] = (vy1 && vx1) ? f2bf(a11) : (u16)0;
        }

        // ---- Phase B1b: d1 (grouped 3x3), one 2x2 task per thread ----------
        {
            int gl = tid >> 6, patch = tid & 63;
            int py = (patch >> 3) * 2, px = (patch & 7) * 2;
            float bias = s_b1[gl];
            float a00 = bias, a01 = bias, a10 = bias, a11 = bias;
#pragma unroll
            for (int j = 0; j < 3; ++j) {
                int lc = (gl < 4) ? (3 * gl + j) : (12 + 3 * (gl - 4) + j);
                const u32* base = (const u32*)&s_xc[lc][0];
                float win[4][4];
#pragma unroll
                for (int r = 0; r < 4; ++r) {
                    int e = (py + 1 + r) * R20 + px;   // even; cols px+1..px+4
                    u32 u0 = base[e >> 1];
                    u32 u1 = base[(e >> 1) + 1];
                    u32 u2 = base[(e >> 1) + 2];
                    win[r][0] = bfhi(u0); win[r][1] = bflo(u1);
                    win[r][2] = bfhi(u1); win[r][3] = bflo(u2);
                }
#pragma unroll
                for (int ky = 0; ky < 3; ++ky)
#pragma unroll
                    for (int kx = 0; kx < 3; ++kx) {
                        float wgt = s_wd1[gl][j * 9 + ky * 3 + kx];
                        a00 = fmaf(wgt, win[ky][kx], a00);
                        a01 = fmaf(wgt, win[ky][kx + 1], a01);
                        a10 = fmaf(wgt, win[ky + 1][kx], a10);
                        a11 = fmaf(wgt, win[ky + 1][kx + 1], a11);
                    }
            }
            u16* drow = &s_d1[gl][py * T + px];
            drow[0] = f2bf(a00); drow[1] = f2bf(a01);
            drow[T] = f2bf(a10); drow[T + 1] = f2bf(a11);
        }
        __syncthreads();

        // ---- Phase B2: d3 = depthwise 3x3 over d3a, one task per thread ----
        {
            int gl = tid >> 6, patch = tid & 63;
            int py = (patch >> 3) * 2, px = (patch & 7) * 2;
            float bias = s_b3b[gl];
            float a00 = bias, a01 = bias, a10 = bias, a11 = bias;
            float win[4][4];
            const u32* base = (const u32*)&s_d3a[gl][0];
#pragma unroll
            for (int r = 0; r < 4; ++r) {
                int e = (py + r) * R18 + px;   // even
                u32 u0 = base[e >> 1];
                u32 u1 = base[(e >> 1) + 1];
                win[r][0] = bflo(u0); win[r][1] = bfhi(u0);
                win[r][2] = bflo(u1); win[r][3] = bfhi(u1);
            }
#pragma unroll
            for (int ky = 0; ky < 3; ++ky)
#pragma unroll
                for (int kx = 0; kx < 3; ++kx) {
                    float wgt = s_wd3b[gl][ky * 3 + kx];
                    a00 = fmaf(wgt, win[ky][kx], a00);
                    a01 = fmaf(wgt, win[ky][kx + 1], a01);
                    a10 = fmaf(wgt, win[ky + 1][kx], a10);
                    a11 = fmaf(wgt, win[ky + 1][kx + 1], a11);
                }
            u16* drow = &s_d3[gl][py * T + px];
            drow[0] = f2bf(a00); drow[1] = f2bf(a01);
            drow[T] = f2bf(a10); drow[T + 1] = f2bf(a11);
        }
        __syncthreads();

        // ---- Phase C: gating + project_out (half0: d1 gates -> ch 0..31,
        //               half1: d3 gates -> ch 32..63) -----------------------
        {
            const u16* sD = (half == 0) ? &s_d1[0][0] : &s_d3[0][0];
            const float* wrow = s_wout + half * 32 * 64;
#pragma unroll
            for (int jp = 0; jp < 2; ++jp) {
                int j0 = 2 * jp;
                float ga = gelu_exact(bf2f(sD[j0 * 256 + pix]))
                         * bf2f(sD[(j0 + 4) * 256 + pix]);
                float gb = gelu_exact(bf2f(sD[(j0 + 1) * 256 + pix]))
                         * bf2f(sD[(j0 + 5) * 256 + pix]);
                int c = c0 + j0;   // even
#pragma unroll
                for (int o = 0; o < 32; ++o) {
                    float2 w2 = *(const float2*)(wrow + o * 64 + c);
                    acc[o] = fmaf(w2.x, ga, acc[o]);
                    acc[o] = fmaf(w2.y, gb, acc[o]);
                }
            }
        }
    }

    // ---- Epilogue: bias + fp32 store --------------------------------------
    {
        int py = pix >> 4, pxx = pix & 15;
        size_t obase = (size_t)b * 64 * HW + (size_t)(half * 32) * HW
                     + (size_t)(oy0 + py) * 256 + (ox0 + pxx);
#pragma unroll
        for (int o = 0; o < 32; ++o)
            outp[obase + (size_t)o * HW] = acc[o] + b_out[half * 32 + o];
    }
}

// ---------------------------------------------------------------------------
// Fallback: fully-fused kernel (used only if ws_size < 201 MB).
// ---------------------------------------------------------------------------
__global__ __launch_bounds__(256, 2)
void ffd_fused(const float* __restrict__ xin, const float* __restrict__ pnin,
               const float* __restrict__ w_in, const float* __restrict__ b_in,
               const float* __restrict__ w_pn, const float* __restrict__ b_pn,
               const float* __restrict__ w_dw1, const float* __restrict__ b_dw1,
               const float* __restrict__ w_dw3a, const float* __restrict__ b_dw3a,
               const float* __restrict__ w_dw3b, const float* __restrict__ b_dw3b,
               const float* __restrict__ w_out, const float* __restrict__ b_out,
               float* __restrict__ outp)
{
    __shared__ __align__(8) u16 s_xc[24][R20 * R20];
    __shared__ __align__(8) float s_d3a[8][R18 * R18];
    __shared__ float s_d1[8][T * T];
    __shared__ float s_d3[8][T * T];
    __shared__ float s_wd1[8][27];
    __shared__ float s_wd3a[8][27];
    __shared__ float s_wd3b[8][9];
    __shared__ float s_b1[8], s_b3a[8], s_b3b[8];

    const int tid = threadIdx.x;
    const int ox0 = blockIdx.x * T;
    const int oy0 = blockIdx.y * T;
    const int b   = blockIdx.z;

    float accL[32], accH[32];
#pragma unroll
    for (int o = 0; o < 32; ++o) { accL[o] = 0.f; accH[o] = 0.f; }

    for (int chunk = 0; chunk < 16; ++chunk) {
        const int c0 = chunk * 4;
        __syncthreads();

        for (int t = tid; t < 512; t += 256) {
            if (t < 216) {
                int gl = t / 27, idx = t - gl * 27;
                int g = (gl < 4) ? (c0 + gl) : (c0 + 60 + gl);
                s_wd1[gl][idx] = w_dw1[g * 27 + idx];
            } else if (t < 432) {
                int t2 = t - 216;
                int gl = t2 / 27, idx = t2 - gl * 27;
                int g = (gl < 4) ? (c0 + gl) : (c0 + 60 + gl);
                s_wd3a[gl][idx] = w_dw3a[g * 27 + idx];
            } else if (t < 504) {
                int t2 = t - 432;
                int gl = t2 / 9, idx = t2 - gl * 9;
                int g = (gl < 4) ? (c0 + gl) : (c0 + 60 + gl);
                s_wd3b[gl][idx] = w_dw3b[g * 9 + idx];
            } else {
                int gl = t - 504;
                int g = (gl < 4) ? (c0 + gl) : (c0 + 60 + gl);
                s_b1[gl]  = b_dw1[g];
                s_b3a[gl] = b_dw3a[g];
                s_b3b[gl] = b_dw3b[g];
            }
        }

        for (int p = tid; p < R20 * R20; p += 256) {
            int py = p / R20, px = p - py * R20;
            int gy = oy0 - 2 + py, gx = ox0 - 2 + px;
            if ((unsigned)gy >= 256u || (unsigned)gx >= 256u) {
#pragma unroll 1
                for (int l = 0; l < 24; ++l) s_xc[l][p] = 0;
                continue;
            }
            const int off = gy * 256 + gx;
            float xr[64];
            const float* xp = xin + (size_t)b * 64 * HW + off;
#pragma unroll
            for (int c = 0; c < 64; ++c) xr[c] = xp[(size_t)c * HW];
            float p0 = 0.f, p1 = 0.f;
            if (3 * c0 < 128) {
                const float* pp = pnin + (size_t)b * 2 * HW + off;
                p0 = pp[0]; p1 = pp[HW];
            }
#pragma unroll 1
            for (int l = 0; l < 24; ++l) {
                int k = (l < 12) ? (3 * c0 + l) : (3 * c0 + 192 + (l - 12));
                float acc;
                if (k < 128) {
                    acc = b_pn[k] + w_pn[2 * k] * p0 + w_pn[2 * k + 1] * p1;
                } else {
                    int kk = k - 128;
                    acc = b_in[kk];
                    const float2* wr = (const float2*)(w_in + kk * 64);
#pragma unroll
                    for (int i = 0; i < 32; ++i) {
                        float2 w2 = wr[i];
                        acc = fmaf(w2.x, xr[2 * i], acc);
                        acc = fmaf(w2.y, xr[2 * i + 1], acc);
                    }
                }
                s_xc[l][p] = f2bf(acc);
            }
        }
        __syncthreads();

        for (int task = tid; task < 8 * 81; task += 256) {
            int gl = task / 81, patch = task - gl * 81;
            int py = (patch / 9) * 2, px = (patch - (patch / 9) * 9) * 2;
            float bias = s_b3a[gl];
            float a00 = bias, a01 = bias, a10 = bias, a11 = bias;
#pragma unroll
            for (int j = 0; j < 3; ++j) {
                int lc = (gl < 4) ? (3 * gl + j) : (12 + 3 * (gl - 4) + j);
                const u32* base = (const u32*)&s_xc[lc][0];
                float win[4][4];
#pragma unroll
                for (int r = 0; r < 4; ++r) {
                    int e = (py + r) * R20 + px;
                    u32 u0 = base[e >> 1];
                    u32 u1 = base[(e >> 1) + 1];
                    win[r][0] = bflo(u0); win[r][1] = bfhi(u0);
                    win[r][2] = bflo(u1); win[r][3] = bfhi(u1);
                }
#pragma unroll
                for (int ky = 0; ky < 3; ++ky)
#pragma unroll
                    for (int kx = 0; kx < 3; ++kx) {
                        float wgt = s_wd3a[gl][j * 9 + ky * 3 + kx];
                        a00 = fmaf(wgt, win[ky][kx], a00);
                        a01 = fmaf(wgt, win[ky][kx + 1], a01);
                        a10 = fmaf(wgt, win[ky + 1][kx], a10);
                        a11 = fmaf(wgt, win[ky + 1][kx + 1], a11);
                    }
            }
            int gy0 = oy0 - 1 + py, gx0 = ox0 - 1 + px;
            bool vy0 = (unsigned)gy0 < 256u, vy1 = (unsigned)(gy0 + 1) < 256u;
            bool vx0 = (unsigned)gx0 < 256u, vx1 = (unsigned)(gx0 + 1) < 256u;
            float* drow = &s_d3a[gl][py * R18 + px];
            drow[0]       = (vy0 && vx0) ? a00 : 0.f;
            drow[1]       = (vy0 && vx1) ? a01 : 0.f;
            drow[R18]     = (vy1 && vx0) ? a10 : 0.f;
            drow[R18 + 1] = (vy1 && vx1) ? a11 : 0.f;
        }

        for (int task = tid; task < 8 * 64; task += 256) {
            int gl = task >> 6, patch = task & 63;
            int py = (patch >> 3) * 2, px = (patch & 7) * 2;
            float bias = s_b1[gl];
            float a00 = bias, a01 = bias, a10 = bias, a11 = bias;
#pragma unroll
            for (int j = 0; j < 3; ++j) {
                int lc = (gl < 4) ? (3 * gl + j) : (12 + 3 * (gl - 4) + j);
                const u32* base = (const u32*)&s_xc[lc][0];
                float win[4][4];
#pragma unroll
                for (int r = 0; r < 4; ++r) {
                    int e = (py + 1 + r) * R20 + px;
                    u32 u0 = base[e >> 1];
                    u32 u1 = base[(e >> 1) + 1];
                    u32 u2 = base[(e >> 1) + 2];
                    win[r][0] = bfhi(u0); win[r][1] = bflo(u1);
                    win[r][2] = bfhi(u1); win[r][3] = bflo(u2);
                }
#pragma unroll
                for (int ky = 0; ky < 3; ++ky)
#pragma unroll
                    for (int kx = 0; kx < 3; ++kx) {
                        float wgt = s_wd1[gl][j * 9 + ky * 3 + kx];
                        a00 = fmaf(wgt, win[ky][kx], a00);
                        a01 = fmaf(wgt, win[ky][kx + 1], a01);
                        a10 = fmaf(wgt, win[ky + 1][kx], a10);
                        a11 = fmaf(wgt, win[ky + 1][kx + 1], a11);
                    }
            }
            float* drow = &s_d1[gl][py * T + px];
            drow[0] = a00; drow[1] = a01; drow[T] = a10; drow[T + 1] = a11;
        }
        __syncthreads();

        for (int task = tid; task < 8 * 64; task += 256) {
            int gl = task >> 6, patch = task & 63;
            int py = (patch >> 3) * 2, px = (patch & 7) * 2;
            float bias = s_b3b[gl];
            float a00 = bias, a01 = bias, a10 = bias, a11 = bias;
            float win[4][4];
#pragma unroll
            for (int r = 0; r < 4; ++r) {
                int e = (py + r) * R18 + px;
                float2 f0 = *(const float2*)&s_d3a[gl][e];
                float2 f1 = *(const float2*)&s_d3a[gl][e + 2];
                win[r][0] = f0.x; win[r][1] = f0.y;
                win[r][2] = f1.x; win[r][3] = f1.y;
            }
#pragma unroll
            for (int ky = 0; ky < 3; ++ky)
#pragma unroll
                for (int kx = 0; kx < 3; ++kx) {
                    float wgt = s_wd3b[gl][ky * 3 + kx];
                    a00 = fmaf(wgt, win[ky][kx], a00);
                    a01 = fmaf(wgt, win[ky][kx + 1], a01);
                    a10 = fmaf(wgt, win[ky + 1][kx], a10);
                    a11 = fmaf(wgt, win[ky + 1][kx + 1], a11);
                }
            float* drow = &s_d3[gl][py * T + px];
            drow[0] = a00; drow[1] = a01; drow[T] = a10; drow[T + 1] = a11;
        }
        __syncthreads();

#pragma unroll
        for (int jp = 0; jp < 2; ++jp) {
            int j0 = 2 * jp;
            float g1a = gelu_exact(s_d1[j0][tid])     * s_d1[j0 + 4][tid];
            float g1b = gelu_exact(s_d1[j0 + 1][tid]) * s_d1[j0 + 5][tid];
            float g2a = gelu_exact(s_d3[j0][tid])     * s_d3[j0 + 4][tid];
            float g2b = gelu_exact(s_d3[j0 + 1][tid]) * s_d3[j0 + 5][tid];
            int c = c0 + j0;
#pragma unroll
            for (int o = 0; o < 32; ++o) {
                float2 wL = *(const float2*)(w_out + o * 64 + c);
                accL[o] = fmaf(wL.x, g1a, accL[o]);
                accL[o] = fmaf(wL.y, g1b, accL[o]);
                float2 wH = *(const float2*)(w_out + (o + 32) * 64 + c);
                accH[o] = fmaf(wH.x, g2a, accH[o]);
                accH[o] = fmaf(wH.y, g2b, accH[o]);
            }
        }
    }

    {
        int py = tid >> 4, pxx = tid & 15;
        size_t obase = (size_t)b * 64 * HW
                     + (size_t)(oy0 + py) * 256 + (ox0 + pxx);
#pragma unroll
        for (int o = 0; o < 32; ++o) {
            outp[obase + (size_t)o * HW]        = accL[o] + b_out[o];
            outp[obase + (size_t)(o + 32) * HW] = accH[o] + b_out[o + 32];
        }
    }
}

extern "C" void kernel_launch(void* const* d_in, const int* in_sizes, int n_in,
                              void* d_out, int out_size, void* d_ws, size_t ws_size,
                              hipStream_t stream) {
    (void)in_sizes; (void)n_in; (void)out_size;
    const float* xin    = (const float*)d_in[0];
    const float* pnin   = (const float*)d_in[1];
    const float* w_in   = (const float*)d_in[2];
    const float* b_in   = (const float*)d_in[3];
    const float* w_pn   = (const float*)d_in[4];
    const float* b_pn   = (const float*)d_in[5];
    const float* w_dw1  = (const float*)d_in[6];
    const float* b_dw1  = (const float*)d_in[7];
    const float* w_dw3a = (const float*)d_in[8];
    const float* b_dw3a = (const float*)d_in[9];
    const float* w_dw3b = (const float*)d_in[10];
    const float* b_dw3b = (const float*)d_in[11];
    const float* w_out  = (const float*)d_in[12];
    const float* b_out  = (const float*)d_in[13];
    float* outp = (float*)d_out;

    if (ws_size >= XC_BYTES) {
        u16* xc = (u16*)d_ws;
        dim3 g1(256, 4), b1(256);
        k1_proj_in<<<g1, b1, 0, stream>>>(xin, pnin, w_in, b_in, w_pn, b_pn, xc);
        dim3 g2(16, 16, 4), b2(512);
        k2_spatial<<<g2, b2, 0, stream>>>(xc, w_dw1, b_dw1, w_dw3a, b_dw3a,
                                          w_dw3b, b_dw3b, w_out, b_out, outp);
    } else {
        dim3 grid(16, 16, 4), blk(256);
        ffd_fused<<<grid, blk, 0, stream>>>(xin, pnin, w_in, b_in, w_pn, b_pn,
                                            w_dw1, b_dw1, w_dw3a, b_dw3a,
                                            w_dw3b, b_dw3b, w_out, b_out, outp);
    }
}

// Round 7
// 755.422 us; speedup vs baseline: 2.1363x; 1.0985x over previous
//
#include <hip/hip_runtime.h>
#include <hip/hip_bf16.h>

// Two-phase FeedForward_denoise:
//   K1: 1x1 projections -> xc bf16 in d_ws, layout [B][16 chunks][HW][24 ch].
//       Weights read as wave-uniform global float4 (L1 broadcast) - r6's LDS
//       staging was LDS-issue bound (16K ds_read_b32/thread -> 415 us).
//   K2: 512 threads/block, 16x16 tile, grouped 3x3 convs, depthwise 3x3,
//       GELU gating, grouped 1x1 project_out. __launch_bounds__(512,2):
//       r5/r6's waves-per-EU=4 squeezed VGPRs to 64 and spilled the 32
//       accumulators to scratch (+350 MB HBM writes).
// Fallback to the fully-fused round-3 kernel if ws_size < 201 MB.

#define T 16
#define R20 20
#define R18 18
#define HW 65536
#define XC_BYTES ((size_t)4 * 16 * HW * 24 * 2)

typedef unsigned short u16;
typedef unsigned int u32;

__device__ __forceinline__ float bflo(u32 w) {
    union { u32 i; float f; } v; v.i = w << 16; return v.f;
}
__device__ __forceinline__ float bfhi(u32 w) {
    union { u32 i; float f; } v; v.i = w & 0xffff0000u; return v.f;
}
__device__ __forceinline__ float bf2f(u16 u) {
    union { u32 i; float f; } v; v.i = ((u32)u) << 16; return v.f;
}
__device__ __forceinline__ u16 f2bf(float f) {
    union { float f; u32 i; } v; v.f = f;
    u32 x = v.i;
    u32 r = (x + 0x7fffu + ((x >> 16) & 1u)) >> 16;
    return (u16)r;
}
__device__ __forceinline__ float gelu_exact(float v) {
    return 0.5f * v * (1.0f + erff(v * 0.70710678118654752f));
}

// ---------------------------------------------------------------------------
// K1: per-pixel 1x1 projections, chunk-pixel-major bf16 output. No LDS;
// weights via uniform global float4 loads (L1-broadcast), 4 FMA chains.
// ---------------------------------------------------------------------------
__global__ __launch_bounds__(256, 2)
void k1_proj_in(const float* __restrict__ xin,   // [4][64][256][256]
                const float* __restrict__ pnin,  // [4][2][256][256]
                const float* __restrict__ w_in,  // [256][64]
                const float* __restrict__ b_in,  // [256]
                const float* __restrict__ w_pn,  // [128][2]
                const float* __restrict__ b_pn,  // [128]
                u16* __restrict__ xc)            // [4][16][HW][24] bf16
{
    const int tid = threadIdx.x;
    const int b = blockIdx.y;
    const int p = blockIdx.x * 256 + tid;   // 0..65535

    float xr[64];
    const float* xp = xin + (size_t)b * 64 * HW + p;
#pragma unroll
    for (int c = 0; c < 64; ++c) xr[c] = xp[(size_t)c * HW];

    const float p0 = pnin[(size_t)b * 2 * HW + p];
    const float p1 = pnin[(size_t)b * 2 * HW + HW + p];

#pragma unroll 1
    for (int chunk = 0; chunk < 16; ++chunk) {
        union { uint4 q[3]; u16 h[24]; } ov;
#pragma unroll 1
        for (int l = 0; l < 24; ++l) {
            int k = (l < 12) ? (12 * chunk + l) : (12 * chunk + 192 + (l - 12));
            float acc;
            if (k < 128) {
                acc = fmaf(w_pn[2 * k], p0,
                      fmaf(w_pn[2 * k + 1], p1, b_pn[k]));
            } else {
                const int kk = k - 128;
                const float4* wr = (const float4*)(w_in + kk * 64);
                float a0 = 0.f, a1 = 0.f, a2 = 0.f, a3 = 0.f;
#pragma unroll
                for (int i = 0; i < 4; ++i) {
                    float4 w0 = wr[4 * i + 0];
                    float4 w1 = wr[4 * i + 1];
                    float4 w2 = wr[4 * i + 2];
                    float4 w3 = wr[4 * i + 3];
                    const int cb = 16 * i;
                    a0 = fmaf(w0.x, xr[cb + 0], a0);
                    a0 = fmaf(w0.y, xr[cb + 1], a0);
                    a0 = fmaf(w0.z, xr[cb + 2], a0);
                    a0 = fmaf(w0.w, xr[cb + 3], a0);
                    a1 = fmaf(w1.x, xr[cb + 4], a1);
                    a1 = fmaf(w1.y, xr[cb + 5], a1);
                    a1 = fmaf(w1.z, xr[cb + 6], a1);
                    a1 = fmaf(w1.w, xr[cb + 7], a1);
                    a2 = fmaf(w2.x, xr[cb + 8], a2);
                    a2 = fmaf(w2.y, xr[cb + 9], a2);
                    a2 = fmaf(w2.z, xr[cb + 10], a2);
                    a2 = fmaf(w2.w, xr[cb + 11], a2);
                    a3 = fmaf(w3.x, xr[cb + 12], a3);
                    a3 = fmaf(w3.y, xr[cb + 13], a3);
                    a3 = fmaf(w3.z, xr[cb + 14], a3);
                    a3 = fmaf(w3.w, xr[cb + 15], a3);
                }
                acc = ((a0 + a1) + (a2 + a3)) + b_in[kk];
            }
            ov.h[l] = f2bf(acc);
        }
        uint4* dst = (uint4*)(xc + ((size_t)(b * 16 + chunk) * HW + p) * 24);
        dst[0] = ov.q[0]; dst[1] = ov.q[1]; dst[2] = ov.q[2];
    }
}

// ---------------------------------------------------------------------------
// K2: spatial convs + gating + project_out. 512 threads, split-half epilogue.
// (512,2): 256-VGPR budget -> no accumulator spill.
// ---------------------------------------------------------------------------
__global__ __launch_bounds__(512, 2)
void k2_spatial(const u16* __restrict__ xc,       // [4][16][HW][24] bf16
                const float* __restrict__ w_dw1,  const float* __restrict__ b_dw1,
                const float* __restrict__ w_dw3a, const float* __restrict__ b_dw3a,
                const float* __restrict__ w_dw3b, const float* __restrict__ b_dw3b,
                const float* __restrict__ w_out,  const float* __restrict__ b_out,
                float* __restrict__ outp)         // [4][64][256][256]
{
    __shared__ __align__(8) u16 s_xc[24][R20 * R20];
    __shared__ __align__(8) u16 s_d3a[8][R18 * R18];
    __shared__ __align__(8) u16 s_d1[8][T * T];
    __shared__ __align__(8) u16 s_d3[8][T * T];
    __shared__ float s_wout[64 * 64];   // 16 KB fp32
    __shared__ float s_wd1[8][27];
    __shared__ float s_wd3a[8][27];
    __shared__ float s_wd3b[8][9];
    __shared__ float s_b1[8], s_b3a[8], s_b3b[8];

    const int tid  = threadIdx.x;
    const int half = tid >> 8;          // wave-uniform (waves 0-3 vs 4-7)
    const int pix  = tid & 255;
    const int ox0 = blockIdx.x * T;
    const int oy0 = blockIdx.y * T;
    const int b   = blockIdx.z;

    // stage w_out once (consumed after the first loop-top barrier)
    for (int i = tid; i < 4096; i += 512) s_wout[i] = w_out[i];

    float acc[32];
#pragma unroll
    for (int o = 0; o < 32; ++o) acc[o] = 0.f;

    for (int chunk = 0; chunk < 16; ++chunk) {
        const int c0 = chunk * 4;
        __syncthreads();   // protect s_* reuse across chunks (+ w_out 1st iter)

        // ---- Phase W: stage chunk weights into LDS -------------------------
        {
            int t = tid;
            if (t < 216) {
                int gl = t / 27, idx = t - gl * 27;
                int g = (gl < 4) ? (c0 + gl) : (c0 + 60 + gl);
                s_wd1[gl][idx] = w_dw1[g * 27 + idx];
            } else if (t < 432) {
                int t2 = t - 216;
                int gl = t2 / 27, idx = t2 - gl * 27;
                int g = (gl < 4) ? (c0 + gl) : (c0 + 60 + gl);
                s_wd3a[gl][idx] = w_dw3a[g * 27 + idx];
            } else if (t < 504) {
                int t2 = t - 432;
                int gl = t2 / 9, idx = t2 - gl * 9;
                int g = (gl < 4) ? (c0 + gl) : (c0 + 60 + gl);
                s_wd3b[gl][idx] = w_dw3b[g * 9 + idx];
            } else if (t < 512) {
                int gl = t - 504;
                int g = (gl < 4) ? (c0 + gl) : (c0 + 60 + gl);
                s_b1[gl]  = b_dw1[g];
                s_b3a[gl] = b_dw3a[g];
                s_b3b[gl] = b_dw3b[g];
            }
        }

        // ---- Phase A: 24 xc channels over 20x20 halo (3 dwordx4 / pixel) ---
        if (tid < 400) {
            int py = tid / R20, px = tid - py * R20;
            int gy = oy0 - 2 + py, gx = ox0 - 2 + px;
            union { uint4 q[3]; u16 h[24]; } v;
            if ((unsigned)gy < 256u && (unsigned)gx < 256u) {
                const uint4* src = (const uint4*)(xc +
                    ((size_t)(b * 16 + chunk) * HW + gy * 256 + gx) * 24);
                v.q[0] = src[0]; v.q[1] = src[1]; v.q[2] = src[2];
            } else {
                v.q[0] = make_uint4(0, 0, 0, 0);
                v.q[1] = make_uint4(0, 0, 0, 0);
                v.q[2] = make_uint4(0, 0, 0, 0);
            }
#pragma unroll
            for (int l = 0; l < 24; ++l) s_xc[l][tid] = v.h[l];
        }
        __syncthreads();

        // ---- Phase B1a: d3a (grouped 3x3) over 18x18, 2x2 per thread -------
        for (int task = tid; task < 8 * 81; task += 512) {
            int gl = task / 81, patch = task - gl * 81;
            int py = (patch / 9) * 2, px = (patch - (patch / 9) * 9) * 2;
            float bias = s_b3a[gl];
            float a00 = bias, a01 = bias, a10 = bias, a11 = bias;
#pragma unroll
            for (int j = 0; j < 3; ++j) {
                int lc = (gl < 4) ? (3 * gl + j) : (12 + 3 * (gl - 4) + j);
                const u32* base = (const u32*)&s_xc[lc][0];
                float win[4][4];
#pragma unroll
                for (int r = 0; r < 4; ++r) {
                    int e = (py + r) * R20 + px;   // even
                    u32 u0 = base[e >> 1];
                    u32 u1 = base[(e >> 1) + 1];
                    win[r][0] = bflo(u0); win[r][1] = bfhi(u0);
                    win[r][2] = bflo(u1); win[r][3] = bfhi(u1);
                }
#pragma unroll
                for (int ky = 0; ky < 3; ++ky)
#pragma unroll
                    for (int kx = 0; kx < 3; ++kx) {
                        float wgt = s_wd3a[gl][j * 9 + ky * 3 + kx];
                        a00 = fmaf(wgt, win[ky][kx], a00);
                        a01 = fmaf(wgt, win[ky][kx + 1], a01);
                        a10 = fmaf(wgt, win[ky + 1][kx], a10);
                        a11 = fmaf(wgt, win[ky + 1][kx + 1], a11);
                    }
            }
            int gy0 = oy0 - 1 + py, gx0 = ox0 - 1 + px;
            bool vy0 = (unsigned)gy0 < 256u, vy1 = (unsigned)(gy0 + 1) < 256u;
            bool vx0 = (unsigned)gx0 < 256u, vx1 = (unsigned)(gx0 + 1) < 256u;
            u16* drow = &s_d3a[gl][py * R18 + px];
            drow[0]       = (vy0 && vx0) ? f2bf(a00) : (u16)0;
            drow[1]       = (vy0 && vx1) ? f2bf(a01) : (u16)0;
            drow[R18]     = (vy1 && vx0) ? f2bf(a10) : (u16)0;
            drow[R18 + 1] = (vy1 && vx1) ? f2bf(a11) : (u16)0;
        }

        // ---- Phase B1b: d1 (grouped 3x3), one 2x2 task per thread ----------
        {
            int gl = tid >> 6, patch = tid & 63;
            int py = (patch >> 3) * 2, px = (patch & 7) * 2;
            float bias = s_b1[gl];
            float a00 = bias, a01 = bias, a10 = bias, a11 = bias;
#pragma unroll
            for (int j = 0; j < 3; ++j) {
                int lc = (gl < 4) ? (3 * gl + j) : (12 + 3 * (gl - 4) + j);
                const u32* base = (const u32*)&s_xc[lc][0];
                float win[4][4];
#pragma unroll
                for (int r = 0; r < 4; ++r) {
                    int e = (py + 1 + r) * R20 + px;   // even; cols px+1..px+4
                    u32 u0 = base[e >> 1];
                    u32 u1 = base[(e >> 1) + 1];
                    u32 u2 = base[(e >> 1) + 2];
                    win[r][0] = bfhi(u0); win[r][1] = bflo(u1);
                    win[r][2] = bfhi(u1); win[r][3] = bflo(u2);
                }
#pragma unroll
                for (int ky = 0; ky < 3; ++ky)
#pragma unroll
                    for (int kx = 0; kx < 3; ++kx) {
                        float wgt = s_wd1[gl][j * 9 + ky * 3 + kx];
                        a00 = fmaf(wgt, win[ky][kx], a00);
                        a01 = fmaf(wgt, win[ky][kx + 1], a01);
                        a10 = fmaf(wgt, win[ky + 1][kx], a10);
                        a11 = fmaf(wgt, win[ky + 1][kx + 1], a11);
                    }
            }
            u16* drow = &s_d1[gl][py * T + px];
            drow[0] = f2bf(a00); drow[1] = f2bf(a01);
            drow[T] = f2bf(a10); drow[T + 1] = f2bf(a11);
        }
        __syncthreads();

        // ---- Phase B2: d3 = depthwise 3x3 over d3a, one task per thread ----
        {
            int gl = tid >> 6, patch = tid & 63;
            int py = (patch >> 3) * 2, px = (patch & 7) * 2;
            float bias = s_b3b[gl];
            float a00 = bias, a01 = bias, a10 = bias, a11 = bias;
            float win[4][4];
            const u32* base = (const u32*)&s_d3a[gl][0];
#pragma unroll
            for (int r = 0; r < 4; ++r) {
                int e = (py + r) * R18 + px;   // even
                u32 u0 = base[e >> 1];
                u32 u1 = base[(e >> 1) + 1];
                win[r][0] = bflo(u0); win[r][1] = bfhi(u0);
                win[r][2] = bflo(u1); win[r][3] = bfhi(u1);
            }
#pragma unroll
            for (int ky = 0; ky < 3; ++ky)
#pragma unroll
                for (int kx = 0; kx < 3; ++kx) {
                    float wgt = s_wd3b[gl][ky * 3 + kx];
                    a00 = fmaf(wgt, win[ky][kx], a00);
                    a01 = fmaf(wgt, win[ky][kx + 1], a01);
                    a10 = fmaf(wgt, win[ky + 1][kx], a10);
                    a11 = fmaf(wgt, win[ky + 1][kx + 1], a11);
                }
            u16* drow = &s_d3[gl][py * T + px];
            drow[0] = f2bf(a00); drow[1] = f2bf(a01);
            drow[T] = f2bf(a10); drow[T + 1] = f2bf(a11);
        }
        __syncthreads();

        // ---- Phase C: gating + project_out (half0: d1 gates -> ch 0..31,
        //               half1: d3 gates -> ch 32..63) -----------------------
        {
            const u16* sD = (half == 0) ? &s_d1[0][0] : &s_d3[0][0];
            const float* wrow = s_wout + half * 32 * 64;
#pragma unroll
            for (int jp = 0; jp < 2; ++jp) {
                int j0 = 2 * jp;
                float ga = gelu_exact(bf2f(sD[j0 * 256 + pix]))
                         * bf2f(sD[(j0 + 4) * 256 + pix]);
                float gb = gelu_exact(bf2f(sD[(j0 + 1) * 256 + pix]))
                         * bf2f(sD[(j0 + 5) * 256 + pix]);
                int c = c0 + j0;   // even
#pragma unroll
                for (int o = 0; o < 32; ++o) {
                    float2 w2 = *(const float2*)(wrow + o * 64 + c);
                    acc[o] = fmaf(w2.x, ga, acc[o]);
                    acc[o] = fmaf(w2.y, gb, acc[o]);
                }
            }
        }
    }

    // ---- Epilogue: bias + fp32 store --------------------------------------
    {
        int py = pix >> 4, pxx = pix & 15;
        size_t obase = (size_t)b * 64 * HW + (size_t)(half * 32) * HW
                     + (size_t)(oy0 + py) * 256 + (ox0 + pxx);
#pragma unroll
        for (int o = 0; o < 32; ++o)
            outp[obase + (size_t)o * HW] = acc[o] + b_out[half * 32 + o];
    }
}

// ---------------------------------------------------------------------------
// Fallback: fully-fused kernel (used only if ws_size < 201 MB).
// ---------------------------------------------------------------------------
__global__ __launch_bounds__(256, 2)
void ffd_fused(const float* __restrict__ xin, const float* __restrict__ pnin,
               const float* __restrict__ w_in, const float* __restrict__ b_in,
               const float* __restrict__ w_pn, const float* __restrict__ b_pn,
               const float* __restrict__ w_dw1, const float* __restrict__ b_dw1,
               const float* __restrict__ w_dw3a, const float* __restrict__ b_dw3a,
               const float* __restrict__ w_dw3b, const float* __restrict__ b_dw3b,
               const float* __restrict__ w_out, const float* __restrict__ b_out,
               float* __restrict__ outp)
{
    __shared__ __align__(8) u16 s_xc[24][R20 * R20];
    __shared__ __align__(8) float s_d3a[8][R18 * R18];
    __shared__ float s_d1[8][T * T];
    __shared__ float s_d3[8][T * T];
    __shared__ float s_wd1[8][27];
    __shared__ float s_wd3a[8][27];
    __shared__ float s_wd3b[8][9];
    __shared__ float s_b1[8], s_b3a[8], s_b3b[8];

    const int tid = threadIdx.x;
    const int ox0 = blockIdx.x * T;
    const int oy0 = blockIdx.y * T;
    const int b   = blockIdx.z;

    float accL[32], accH[32];
#pragma unroll
    for (int o = 0; o < 32; ++o) { accL[o] = 0.f; accH[o] = 0.f; }

    for (int chunk = 0; chunk < 16; ++chunk) {
        const int c0 = chunk * 4;
        __syncthreads();

        for (int t = tid; t < 512; t += 256) {
            if (t < 216) {
                int gl = t / 27, idx = t - gl * 27;
                int g = (gl < 4) ? (c0 + gl) : (c0 + 60 + gl);
                s_wd1[gl][idx] = w_dw1[g * 27 + idx];
            } else if (t < 432) {
                int t2 = t - 216;
                int gl = t2 / 27, idx = t2 - gl * 27;
                int g = (gl < 4) ? (c0 + gl) : (c0 + 60 + gl);
                s_wd3a[gl][idx] = w_dw3a[g * 27 + idx];
            } else if (t < 504) {
                int t2 = t - 432;
                int gl = t2 / 9, idx = t2 - gl * 9;
                int g = (gl < 4) ? (c0 + gl) : (c0 + 60 + gl);
                s_wd3b[gl][idx] = w_dw3b[g * 9 + idx];
            } else {
                int gl = t - 504;
                int g = (gl < 4) ? (c0 + gl) : (c0 + 60 + gl);
                s_b1[gl]  = b_dw1[g];
                s_b3a[gl] = b_dw3a[g];
                s_b3b[gl] = b_dw3b[g];
            }
        }

        for (int p = tid; p < R20 * R20; p += 256) {
            int py = p / R20, px = p - py * R20;
            int gy = oy0 - 2 + py, gx = ox0 - 2 + px;
            if ((unsigned)gy >= 256u || (unsigned)gx >= 256u) {
#pragma unroll 1
                for (int l = 0; l < 24; ++l) s_xc[l][p] = 0;
                continue;
            }
            const int off = gy * 256 + gx;
            float xr[64];
            const float* xp = xin + (size_t)b * 64 * HW + off;
#pragma unroll
            for (int c = 0; c < 64; ++c) xr[c] = xp[(size_t)c * HW];
            float p0 = 0.f, p1 = 0.f;
            if (3 * c0 < 128) {
                const float* pp = pnin + (size_t)b * 2 * HW + off;
                p0 = pp[0]; p1 = pp[HW];
            }
#pragma unroll 1
            for (int l = 0; l < 24; ++l) {
                int k = (l < 12) ? (3 * c0 + l) : (3 * c0 + 192 + (l - 12));
                float acc;
                if (k < 128) {
                    acc = b_pn[k] + w_pn[2 * k] * p0 + w_pn[2 * k + 1] * p1;
                } else {
                    int kk = k - 128;
                    acc = b_in[kk];
                    const float2* wr = (const float2*)(w_in + kk * 64);
#pragma unroll
                    for (int i = 0; i < 32; ++i) {
                        float2 w2 = wr[i];
                        acc = fmaf(w2.x, xr[2 * i], acc);
                        acc = fmaf(w2.y, xr[2 * i + 1], acc);
                    }
                }
                s_xc[l][p] = f2bf(acc);
            }
        }
        __syncthreads();

        for (int task = tid; task < 8 * 81; task += 256) {
            int gl = task / 81, patch = task - gl * 81;
            int py = (patch / 9) * 2, px = (patch - (patch / 9) * 9) * 2;
            float bias = s_b3a[gl];
            float a00 = bias, a01 = bias, a10 = bias, a11 = bias;
#pragma unroll
            for (int j = 0; j < 3; ++j) {
                int lc = (gl < 4) ? (3 * gl + j) : (12 + 3 * (gl - 4) + j);
                const u32* base = (const u32*)&s_xc[lc][0];
                float win[4][4];
#pragma unroll
                for (int r = 0; r < 4; ++r) {
                    int e = (py + r) * R20 + px;
                    u32 u0 = base[e >> 1];
                    u32 u1 = base[(e >> 1) + 1];
                    win[r][0] = bflo(u0); win[r][1] = bfhi(u0);
                    win[r][2] = bflo(u1); win[r][3] = bfhi(u1);
                }
#pragma unroll
                for (int ky = 0; ky < 3; ++ky)
#pragma unroll
                    for (int kx = 0; kx < 3; ++kx) {
                        float wgt = s_wd3a[gl][j * 9 + ky * 3 + kx];
                        a00 = fmaf(wgt, win[ky][kx], a00);
                        a01 = fmaf(wgt, win[ky][kx + 1], a01);
                        a10 = fmaf(wgt, win[ky + 1][kx], a10);
                        a11 = fmaf(wgt, win[ky + 1][kx + 1], a11);
                    }
            }
            int gy0 = oy0 - 1 + py, gx0 = ox0 - 1 + px;
            bool vy0 = (unsigned)gy0 < 256u, vy1 = (unsigned)(gy0 + 1) < 256u;
            bool vx0 = (unsigned)gx0 < 256u, vx1 = (unsigned)(gx0 + 1) < 256u;
            float* drow = &s_d3a[gl][py * R18 + px];
            drow[0]       = (vy0 && vx0) ? a00 : 0.f;
            drow[1]       = (vy0 && vx1) ? a01 : 0.f;
            drow[R18]     = (vy1 && vx0) ? a10 : 0.f;
            drow[R18 + 1] = (vy1 && vx1) ? a11 : 0.f;
        }

        for (int task = tid; task < 8 * 64; task += 256) {
            int gl = task >> 6, patch = task & 63;
            int py = (patch >> 3) * 2, px = (patch & 7) * 2;
            float bias = s_b1[gl];
            float a00 = bias, a01 = bias, a10 = bias, a11 = bias;
#pragma unroll
            for (int j = 0; j < 3; ++j) {
                int lc = (gl < 4) ? (3 * gl + j) : (12 + 3 * (gl - 4) + j);
                const u32* base = (const u32*)&s_xc[lc][0];
                float win[4][4];
#pragma unroll
                for (int r = 0; r < 4; ++r) {
                    int e = (py + 1 + r) * R20 + px;
                    u32 u0 = base[e >> 1];
                    u32 u1 = base[(e >> 1) + 1];
                    u32 u2 = base[(e >> 1) + 2];
                    win[r][0] = bfhi(u0); win[r][1] = bflo(u1);
                    win[r][2] = bfhi(u1); win[r][3] = bflo(u2);
                }
#pragma unroll
                for (int ky = 0; ky < 3; ++ky)
#pragma unroll
                    for (int kx = 0; kx < 3; ++kx) {
                        float wgt = s_wd1[gl][j * 9 + ky * 3 + kx];
                        a00 = fmaf(wgt, win[ky][kx], a00);
                        a01 = fmaf(wgt, win[ky][kx + 1], a01);
                        a10 = fmaf(wgt, win[ky + 1][kx], a10);
                        a11 = fmaf(wgt, win[ky + 1][kx + 1], a11);
                    }
            }
            float* drow = &s_d1[gl][py * T + px];
            drow[0] = a00; drow[1] = a01; drow[T] = a10; drow[T + 1] = a11;
        }
        __syncthreads();

        for (int task = tid; task < 8 * 64; task += 256) {
            int gl = task >> 6, patch = task & 63;
            int py = (patch >> 3) * 2, px = (patch & 7) * 2;
            float bias = s_b3b[gl];
            float a00 = bias, a01 = bias, a10 = bias, a11 = bias;
            float win[4][4];
#pragma unroll
            for (int r = 0; r < 4; ++r) {
                int e = (py + r) * R18 + px;
                float2 f0 = *(const float2*)&s_d3a[gl][e];
                float2 f1 = *(const float2*)&s_d3a[gl][e + 2];
                win[r][0] = f0.x; win[r][1] = f0.y;
                win[r][2] = f1.x; win[r][3] = f1.y;
            }
#pragma unroll
            for (int ky = 0; ky < 3; ++ky)
#pragma unroll
                for (int kx = 0; kx < 3; ++kx) {
                    float wgt = s_wd3b[gl][ky * 3 + kx];
                    a00 = fmaf(wgt, win[ky][kx], a00);
                    a01 = fmaf(wgt, win[ky][kx + 1], a01);
                    a10 = fmaf(wgt, win[ky + 1][kx], a10);
                    a11 = fmaf(wgt, win[ky + 1][kx + 1], a11);
                }
            float* drow = &s_d3[gl][py * T + px];
            drow[0] = a00; drow[1] = a01; drow[T] = a10; drow[T + 1] = a11;
        }
        __syncthreads();

#pragma unroll
        for (int jp = 0; jp < 2; ++jp) {
            int j0 = 2 * jp;
            float g1a = gelu_exact(s_d1[j0][tid])     * s_d1[j0 + 4][tid];
            float g1b = gelu_exact(s_d1[j0 + 1][tid]) * s_d1[j0 + 5][tid];
            float g2a = gelu_exact(s_d3[j0][tid])     * s_d3[j0 + 4][tid];
            float g2b = gelu_exact(s_d3[j0 + 1][tid]) * s_d3[j0 + 5][tid];
            int c = c0 + j0;
#pragma unroll
            for (int o = 0; o < 32; ++o) {
                float2 wL = *(const float2*)(w_out + o * 64 + c);
                accL[o] = fmaf(wL.x, g1a, accL[o]);
                accL[o] = fmaf(wL.y, g1b, accL[o]);
                float2 wH = *(const float2*)(w_out + (o + 32) * 64 + c);
                accH[o] = fmaf(wH.x, g2a, accH[o]);
                accH[o] = fmaf(wH.y, g2b, accH[o]);
            }
        }
    }

    {
        int py = tid >> 4, pxx = tid & 15;
        size_t obase = (size_t)b * 64 * HW
                     + (size_t)(oy0 + py) * 256 + (ox0 + pxx);
#pragma unroll
        for (int o = 0; o < 32; ++o) {
            outp[obase + (size_t)o * HW]        = accL[o] + b_out[o];
            outp[obase + (size_t)(o + 32) * HW] = accH[o] + b_out[o + 32];
        }
    }
}

extern "C" void kernel_launch(void* const* d_in, const int* in_sizes, int n_in,
                              void* d_out, int out_size, void* d_ws, size_t ws_size,
                              hipStream_t stream) {
    (void)in_sizes; (void)n_in; (void)out_size;
    const float* xin    = (const float*)d_in[0];
    const float* pnin   = (const float*)d_in[1];
    const float* w_in   = (const float*)d_in[2];
    const float* b_in   = (const float*)d_in[3];
    const float* w_pn   = (const float*)d_in[4];
    const float* b_pn   = (const float*)d_in[5];
    const float* w_dw1  = (const float*)d_in[6];
    const float* b_dw1  = (const float*)d_in[7];
    const float* w_dw3a = (const float*)d_in[8];
    const float* b_dw3a = (const float*)d_in[9];
    const float* w_dw3b = (const float*)d_in[10];
    const float* b_dw3b = (const float*)d_in[11];
    const float* w_out  = (const float*)d_in[12];
    const float* b_out  = (const float*)d_in[13];
    float* outp = (float*)d_out;

    if (ws_size >= XC_BYTES) {
        u16* xc = (u16*)d_ws;
        dim3 g1(256, 4), b1(256);
        k1_proj_in<<<g1, b1, 0, stream>>>(xin, pnin, w_in, b_in, w_pn, b_pn, xc);
        dim3 g2(16, 16, 4), b2(512);
        k2_spatial<<<g2, b2, 0, stream>>>(xc, w_dw1, b_dw1, w_dw3a, b_dw3a,
                                          w_dw3b, b_dw3b, w_out, b_out, outp);
    } else {
        dim3 grid(16, 16, 4), blk(256);
        ffd_fused<<<grid, blk, 0, stream>>>(xin, pnin, w_in, b_in, w_pn, b_pn,
                                            w_dw1, b_dw1, w_dw3a, b_dw3a,
                                            w_dw3b, b_dw3b, w_out, b_out, outp);
    }
}

// Round 8
// 641.259 us; speedup vs baseline: 2.5167x; 1.1780x over previous
//
#include <hip/hip_runtime.h>
#include <hip/hip_bf16.h>

// Two-phase FeedForward_denoise:
//   K1: 1x1 projections -> xc bf16 in d_ws, layout [B][16 chunks][HW][24 ch].
//       LDS-staged VALU GEMM: w_in (64 KB) in LDS read via broadcast
//       ds_read_b128; 2 pixels/thread so 16 LDS reads serve 128 FMAs
//       (VALU-bound). r5-r7 variants all ~320-415 us because each thread's
//       64 KB w working set thrashed the 32 KB L1 (per-row L2 latency).
//   K2: 512 threads/block, 16x16 tile, grouped 3x3 convs, depthwise 3x3,
//       GELU gating, grouped 1x1 project_out. (512,2): no accumulator spill.
// Fallback to the fully-fused kernel if ws_size < 201 MB.

#define T 16
#define R20 20
#define R18 18
#define HW 65536
#define XC_BYTES ((size_t)4 * 16 * HW * 24 * 2)

typedef unsigned short u16;
typedef unsigned int u32;

__device__ __forceinline__ float bflo(u32 w) {
    union { u32 i; float f; } v; v.i = w << 16; return v.f;
}
__device__ __forceinline__ float bfhi(u32 w) {
    union { u32 i; float f; } v; v.i = w & 0xffff0000u; return v.f;
}
__device__ __forceinline__ float bf2f(u16 u) {
    union { u32 i; float f; } v; v.i = ((u32)u) << 16; return v.f;
}
__device__ __forceinline__ u16 f2bf(float f) {
    union { float f; u32 i; } v; v.f = f;
    u32 x = v.i;
    u32 r = (x + 0x7fffu + ((x >> 16) & 1u)) >> 16;
    return (u16)r;
}
__device__ __forceinline__ float gelu_exact(float v) {
    return 0.5f * v * (1.0f + erff(v * 0.70710678118654752f));
}

// ---------------------------------------------------------------------------
// K1: LDS-staged fp32 GEMM, 2 pixels/thread, chunk-pixel-major bf16 output.
// ---------------------------------------------------------------------------
__global__ __launch_bounds__(256, 2)
void k1_proj_in(const float* __restrict__ xin,   // [4][64][256][256]
                const float* __restrict__ pnin,  // [4][2][256][256]
                const float* __restrict__ w_in,  // [256][64]
                const float* __restrict__ b_in,  // [256]
                const float* __restrict__ w_pn,  // [128][2]
                const float* __restrict__ b_pn,  // [128]
                u16* __restrict__ xc)            // [4][16][HW][24] bf16
{
    __shared__ float4 s_w4[256 * 16];   // w_in rows as float4: 64 KB
    __shared__ float s_bin[256];
    __shared__ float s_wpn[256];
    __shared__ float s_bpn[128];

    const int tid = threadIdx.x;

    // stage w_in (coalesced float4) + small tables
    for (int i = tid; i < 4096; i += 256) s_w4[i] = ((const float4*)w_in)[i];
    s_bin[tid] = b_in[tid];
    s_wpn[tid] = w_pn[tid];
    if (tid < 128) s_bpn[tid] = b_pn[tid];
    __syncthreads();

    const int b  = blockIdx.y;
    const int pp = blockIdx.x * 256 + tid;   // float2 pixel-pair index, 0..32767
    const int p0 = pp * 2;

    // x for 2 pixels: 64 float2 = 128 VGPRs, coalesced dwordx2 loads
    float2 xr[64];
    const float2* xp2 = (const float2*)(xin + (size_t)b * 64 * HW);
#pragma unroll
    for (int c = 0; c < 64; ++c) xr[c] = xp2[(size_t)c * (HW / 2) + pp];

    const float2 pn0 = ((const float2*)(pnin + (size_t)b * 2 * HW))[pp];
    const float2 pn1 = ((const float2*)(pnin + (size_t)b * 2 * HW + HW))[pp];

#pragma unroll 1
    for (int chunk = 0; chunk < 16; ++chunk) {
        union { uint4 q[6]; u16 h[48]; } ov;   // [pix0 24ch][pix1 24ch]
#pragma unroll 1
        for (int l = 0; l < 24; ++l) {
            int k = (l < 12) ? (12 * chunk + l) : (12 * chunk + 192 + (l - 12));
            float accx, accy;
            if (k < 128) {
                float wa = s_wpn[2 * k], wb = s_wpn[2 * k + 1], bb = s_bpn[k];
                accx = fmaf(wa, pn0.x, fmaf(wb, pn1.x, bb));
                accy = fmaf(wa, pn0.y, fmaf(wb, pn1.y, bb));
            } else {
                const int kk = k - 128;
                const float4* wr = &s_w4[kk * 16];
                float a0x = 0.f, a1x = 0.f, a2x = 0.f, a3x = 0.f;
                float a0y = 0.f, a1y = 0.f, a2y = 0.f, a3y = 0.f;
#pragma unroll
                for (int i = 0; i < 4; ++i) {
                    float4 w0 = wr[4 * i + 0];
                    float4 w1 = wr[4 * i + 1];
                    float4 w2 = wr[4 * i + 2];
                    float4 w3 = wr[4 * i + 3];
                    const int cb = 16 * i;
                    a0x = fmaf(w0.x, xr[cb + 0].x, a0x);  a0y = fmaf(w0.x, xr[cb + 0].y, a0y);
                    a0x = fmaf(w0.y, xr[cb + 1].x, a0x);  a0y = fmaf(w0.y, xr[cb + 1].y, a0y);
                    a0x = fmaf(w0.z, xr[cb + 2].x, a0x);  a0y = fmaf(w0.z, xr[cb + 2].y, a0y);
                    a0x = fmaf(w0.w, xr[cb + 3].x, a0x);  a0y = fmaf(w0.w, xr[cb + 3].y, a0y);
                    a1x = fmaf(w1.x, xr[cb + 4].x, a1x);  a1y = fmaf(w1.x, xr[cb + 4].y, a1y);
                    a1x = fmaf(w1.y, xr[cb + 5].x, a1x);  a1y = fmaf(w1.y, xr[cb + 5].y, a1y);
                    a1x = fmaf(w1.z, xr[cb + 6].x, a1x);  a1y = fmaf(w1.z, xr[cb + 6].y, a1y);
                    a1x = fmaf(w1.w, xr[cb + 7].x, a1x);  a1y = fmaf(w1.w, xr[cb + 7].y, a1y);
                    a2x = fmaf(w2.x, xr[cb + 8].x, a2x);  a2y = fmaf(w2.x, xr[cb + 8].y, a2y);
                    a2x = fmaf(w2.y, xr[cb + 9].x, a2x);  a2y = fmaf(w2.y, xr[cb + 9].y, a2y);
                    a2x = fmaf(w2.z, xr[cb + 10].x, a2x); a2y = fmaf(w2.z, xr[cb + 10].y, a2y);
                    a2x = fmaf(w2.w, xr[cb + 11].x, a2x); a2y = fmaf(w2.w, xr[cb + 11].y, a2y);
                    a3x = fmaf(w3.x, xr[cb + 12].x, a3x); a3y = fmaf(w3.x, xr[cb + 12].y, a3y);
                    a3x = fmaf(w3.y, xr[cb + 13].x, a3x); a3y = fmaf(w3.y, xr[cb + 13].y, a3y);
                    a3x = fmaf(w3.z, xr[cb + 14].x, a3x); a3y = fmaf(w3.z, xr[cb + 14].y, a3y);
                    a3x = fmaf(w3.w, xr[cb + 15].x, a3x); a3y = fmaf(w3.w, xr[cb + 15].y, a3y);
                }
                float bb = s_bin[kk];
                accx = ((a0x + a1x) + (a2x + a3x)) + bb;
                accy = ((a0y + a1y) + (a2y + a3y)) + bb;
            }
            ov.h[l] = f2bf(accx);
            ov.h[24 + l] = f2bf(accy);
        }
        // 2 pixels x 48 B contiguous = 96 B dense store
        uint4* dst = (uint4*)(xc + ((size_t)(b * 16 + chunk) * HW + p0) * 24);
        dst[0] = ov.q[0]; dst[1] = ov.q[1]; dst[2] = ov.q[2];
        dst[3] = ov.q[3]; dst[4] = ov.q[4]; dst[5] = ov.q[5];
    }
}

// ---------------------------------------------------------------------------
// K2: spatial convs + gating + project_out. 512 threads, split-half epilogue.
// (unchanged from round 7)
// ---------------------------------------------------------------------------
__global__ __launch_bounds__(512, 2)
void k2_spatial(const u16* __restrict__ xc,       // [4][16][HW][24] bf16
                const float* __restrict__ w_dw1,  const float* __restrict__ b_dw1,
                const float* __restrict__ w_dw3a, const float* __restrict__ b_dw3a,
                const float* __restrict__ w_dw3b, const float* __restrict__ b_dw3b,
                const float* __restrict__ w_out,  const float* __restrict__ b_out,
                float* __restrict__ outp)         // [4][64][256][256]
{
    __shared__ __align__(8) u16 s_xc[24][R20 * R20];
    __shared__ __align__(8) u16 s_d3a[8][R18 * R18];
    __shared__ __align__(8) u16 s_d1[8][T * T];
    __shared__ __align__(8) u16 s_d3[8][T * T];
    __shared__ float s_wout[64 * 64];   // 16 KB fp32
    __shared__ float s_wd1[8][27];
    __shared__ float s_wd3a[8][27];
    __shared__ float s_wd3b[8][9];
    __shared__ float s_b1[8], s_b3a[8], s_b3b[8];

    const int tid  = threadIdx.x;
    const int half = tid >> 8;          // wave-uniform (waves 0-3 vs 4-7)
    const int pix  = tid & 255;
    const int ox0 = blockIdx.x * T;
    const int oy0 = blockIdx.y * T;
    const int b   = blockIdx.z;

    // stage w_out once (consumed after the first loop-top barrier)
    for (int i = tid; i < 4096; i += 512) s_wout[i] = w_out[i];

    float acc[32];
#pragma unroll
    for (int o = 0; o < 32; ++o) acc[o] = 0.f;

    for (int chunk = 0; chunk < 16; ++chunk) {
        const int c0 = chunk * 4;
        __syncthreads();   // protect s_* reuse across chunks (+ w_out 1st iter)

        // ---- Phase W: stage chunk weights into LDS -------------------------
        {
            int t = tid;
            if (t < 216) {
                int gl = t / 27, idx = t - gl * 27;
                int g = (gl < 4) ? (c0 + gl) : (c0 + 60 + gl);
                s_wd1[gl][idx] = w_dw1[g * 27 + idx];
            } else if (t < 432) {
                int t2 = t - 216;
                int gl = t2 / 27, idx = t2 - gl * 27;
                int g = (gl < 4) ? (c0 + gl) : (c0 + 60 + gl);
                s_wd3a[gl][idx] = w_dw3a[g * 27 + idx];
            } else if (t < 504) {
                int t2 = t - 432;
                int gl = t2 / 9, idx = t2 - gl * 9;
                int g = (gl < 4) ? (c0 + gl) : (c0 + 60 + gl);
                s_wd3b[gl][idx] = w_dw3b[g * 9 + idx];
            } else if (t < 512) {
                int gl = t - 504;
                int g = (gl < 4) ? (c0 + gl) : (c0 + 60 + gl);
                s_b1[gl]  = b_dw1[g];
                s_b3a[gl] = b_dw3a[g];
                s_b3b[gl] = b_dw3b[g];
            }
        }

        // ---- Phase A: 24 xc channels over 20x20 halo (3 dwordx4 / pixel) ---
        if (tid < 400) {
            int py = tid / R20, px = tid - py * R20;
            int gy = oy0 - 2 + py, gx = ox0 - 2 + px;
            union { uint4 q[3]; u16 h[24]; } v;
            if ((unsigned)gy < 256u && (unsigned)gx < 256u) {
                const uint4* src = (const uint4*)(xc +
                    ((size_t)(b * 16 + chunk) * HW + gy * 256 + gx) * 24);
                v.q[0] = src[0]; v.q[1] = src[1]; v.q[2] = src[2];
            } else {
                v.q[0] = make_uint4(0, 0, 0, 0);
                v.q[1] = make_uint4(0, 0, 0, 0);
                v.q[2] = make_uint4(0, 0, 0, 0);
            }
#pragma unroll
            for (int l = 0; l < 24; ++l) s_xc[l][tid] = v.h[l];
        }
        __syncthreads();

        // ---- Phase B1a: d3a (grouped 3x3) over 18x18, 2x2 per thread -------
        for (int task = tid; task < 8 * 81; task += 512) {
            int gl = task / 81, patch = task - gl * 81;
            int py = (patch / 9) * 2, px = (patch - (patch / 9) * 9) * 2;
            float bias = s_b3a[gl];
            float a00 = bias, a01 = bias, a10 = bias, a11 = bias;
#pragma unroll
            for (int j = 0; j < 3; ++j) {
                int lc = (gl < 4) ? (3 * gl + j) : (12 + 3 * (gl - 4) + j);
                const u32* base = (const u32*)&s_xc[lc][0];
                float win[4][4];
#pragma unroll
                for (int r = 0; r < 4; ++r) {
                    int e = (py + r) * R20 + px;   // even
                    u32 u0 = base[e >> 1];
                    u32 u1 = base[(e >> 1) + 1];
                    win[r][0] = bflo(u0); win[r][1] = bfhi(u0);
                    win[r][2] = bflo(u1); win[r][3] = bfhi(u1);
                }
#pragma unroll
                for (int ky = 0; ky < 3; ++ky)
#pragma unroll
                    for (int kx = 0; kx < 3; ++kx) {
                        float wgt = s_wd3a[gl][j * 9 + ky * 3 + kx];
                        a00 = fmaf(wgt, win[ky][kx], a00);
                        a01 = fmaf(wgt, win[ky][kx + 1], a01);
                        a10 = fmaf(wgt, win[ky + 1][kx], a10);
                        a11 = fmaf(wgt, win[ky + 1][kx + 1], a11);
                    }
            }
            int gy0 = oy0 - 1 + py, gx0 = ox0 - 1 + px;
            bool vy0 = (unsigned)gy0 < 256u, vy1 = (unsigned)(gy0 + 1) < 256u;
            bool vx0 = (unsigned)gx0 < 256u, vx1 = (unsigned)(gx0 + 1) < 256u;
            u16* drow = &s_d3a[gl][py * R18 + px];
            drow[0]       = (vy0 && vx0) ? f2bf(a00) : (u16)0;
            drow[1]       = (vy0 && vx1) ? f2bf(a01) : (u16)0;
            drow[R18]     = (vy1 && vx0) ? f2bf(a10) : (u16)0;
            drow[R18 + 1] = (vy1 && vx1) ? f2bf(a11) : (u16)0;
        }

        // ---- Phase B1b: d1 (grouped 3x3), one 2x2 task per thread ----------
        {
            int gl = tid >> 6, patch = tid & 63;
            int py = (patch >> 3) * 2, px = (patch & 7) * 2;
            float bias = s_b1[gl];
            float a00 = bias, a01 = bias, a10 = bias, a11 = bias;
#pragma unroll
            for (int j = 0; j < 3; ++j) {
                int lc = (gl < 4) ? (3 * gl + j) : (12 + 3 * (gl - 4) + j);
                const u32* base = (const u32*)&s_xc[lc][0];
                float win[4][4];
#pragma unroll
                for (int r = 0; r < 4; ++r) {
                    int e = (py + 1 + r) * R20 + px;   // even; cols px+1..px+4
                    u32 u0 = base[e >> 1];
                    u32 u1 = base[(e >> 1) + 1];
                    u32 u2 = base[(e >> 1) + 2];
                    win[r][0] = bfhi(u0); win[r][1] = bflo(u1);
                    win[r][2] = bfhi(u1); win[r][3] = bflo(u2);
                }
#pragma unroll
                for (int ky = 0; ky < 3; ++ky)
#pragma unroll
                    for (int kx = 0; kx < 3; ++kx) {
                        float wgt = s_wd1[gl][j * 9 + ky * 3 + kx];
                        a00 = fmaf(wgt, win[ky][kx], a00);
                        a01 = fmaf(wgt, win[ky][kx + 1], a01);
                        a10 = fmaf(wgt, win[ky + 1][kx], a10);
                        a11 = fmaf(wgt, win[ky + 1][kx + 1], a11);
                    }
            }
            u16* drow = &s_d1[gl][py * T + px];
            drow[0] = f2bf(a00); drow[1] = f2bf(a01);
            drow[T] = f2bf(a10); drow[T + 1] = f2bf(a11);
        }
        __syncthreads();

        // ---- Phase B2: d3 = depthwise 3x3 over d3a, one task per thread ----
        {
            int gl = tid >> 6, patch = tid & 63;
            int py = (patch >> 3) * 2, px = (patch & 7) * 2;
            float bias = s_b3b[gl];
            float a00 = bias, a01 = bias, a10 = bias, a11 = bias;
            float win[4][4];
            const u32* base = (const u32*)&s_d3a[gl][0];
#pragma unroll
            for (int r = 0; r < 4; ++r) {
                int e = (py + r) * R18 + px;   // even
                u32 u0 = base[e >> 1];
                u32 u1 = base[(e >> 1) + 1];
                win[r][0] = bflo(u0); win[r][1] = bfhi(u0);
                win[r][2] = bflo(u1); win[r][3] = bfhi(u1);
            }
#pragma unroll
            for (int ky = 0; ky < 3; ++ky)
#pragma unroll
                for (int kx = 0; kx < 3; ++kx) {
                    float wgt = s_wd3b[gl][ky * 3 + kx];
                    a00 = fmaf(wgt, win[ky][kx], a00);
                    a01 = fmaf(wgt, win[ky][kx + 1], a01);
                    a10 = fmaf(wgt, win[ky + 1][kx], a10);
                    a11 = fmaf(wgt, win[ky + 1][kx + 1], a11);
                }
            u16* drow = &s_d3[gl][py * T + px];
            drow[0] = f2bf(a00); drow[1] = f2bf(a01);
            drow[T] = f2bf(a10); drow[T + 1] = f2bf(a11);
        }
        __syncthreads();

        // ---- Phase C: gating + project_out (half0: d1 gates -> ch 0..31,
        //               half1: d3 gates -> ch 32..63) -----------------------
        {
            const u16* sD = (half == 0) ? &s_d1[0][0] : &s_d3[0][0];
            const float* wrow = s_wout + half * 32 * 64;
#pragma unroll
            for (int jp = 0; jp < 2; ++jp) {
                int j0 = 2 * jp;
                float ga = gelu_exact(bf2f(sD[j0 * 256 + pix]))
                         * bf2f(sD[(j0 + 4) * 256 + pix]);
                float gb = gelu_exact(bf2f(sD[(j0 + 1) * 256 + pix]))
                         * bf2f(sD[(j0 + 5) * 256 + pix]);
                int c = c0 + j0;   // even
#pragma unroll
                for (int o = 0; o < 32; ++o) {
                    float2 w2 = *(const float2*)(wrow + o * 64 + c);
                    acc[o] = fmaf(w2.x, ga, acc[o]);
                    acc[o] = fmaf(w2.y, gb, acc[o]);
                }
            }
        }
    }

    // ---- Epilogue: bias + fp32 store --------------------------------------
    {
        int py = pix >> 4, pxx = pix & 15;
        size_t obase = (size_t)b * 64 * HW + (size_t)(half * 32) * HW
                     + (size_t)(oy0 + py) * 256 + (ox0 + pxx);
#pragma unroll
        for (int o = 0; o < 32; ++o)
            outp[obase + (size_t)o * HW] = acc[o] + b_out[half * 32 + o];
    }
}

// ---------------------------------------------------------------------------
// Fallback: fully-fused kernel (used only if ws_size < 201 MB).
// ---------------------------------------------------------------------------
__global__ __launch_bounds__(256, 2)
void ffd_fused(const float* __restrict__ xin, const float* __restrict__ pnin,
               const float* __restrict__ w_in, const float* __restrict__ b_in,
               const float* __restrict__ w_pn, const float* __restrict__ b_pn,
               const float* __restrict__ w_dw1, const float* __restrict__ b_dw1,
               const float* __restrict__ w_dw3a, const float* __restrict__ b_dw3a,
               const float* __restrict__ w_dw3b, const float* __restrict__ b_dw3b,
               const float* __restrict__ w_out, const float* __restrict__ b_out,
               float* __restrict__ outp)
{
    __shared__ __align__(8) u16 s_xc[24][R20 * R20];
    __shared__ __align__(8) float s_d3a[8][R18 * R18];
    __shared__ float s_d1[8][T * T];
    __shared__ float s_d3[8][T * T];
    __shared__ float s_wd1[8][27];
    __shared__ float s_wd3a[8][27];
    __shared__ float s_wd3b[8][9];
    __shared__ float s_b1[8], s_b3a[8], s_b3b[8];

    const int tid = threadIdx.x;
    const int ox0 = blockIdx.x * T;
    const int oy0 = blockIdx.y * T;
    const int b   = blockIdx.z;

    float accL[32], accH[32];
#pragma unroll
    for (int o = 0; o < 32; ++o) { accL[o] = 0.f; accH[o] = 0.f; }

    for (int chunk = 0; chunk < 16; ++chunk) {
        const int c0 = chunk * 4;
        __syncthreads();

        for (int t = tid; t < 512; t += 256) {
            if (t < 216) {
                int gl = t / 27, idx = t - gl * 27;
                int g = (gl < 4) ? (c0 + gl) : (c0 + 60 + gl);
                s_wd1[gl][idx] = w_dw1[g * 27 + idx];
            } else if (t < 432) {
                int t2 = t - 216;
                int gl = t2 / 27, idx = t2 - gl * 27;
                int g = (gl < 4) ? (c0 + gl) : (c0 + 60 + gl);
                s_wd3a[gl][idx] = w_dw3a[g * 27 + idx];
            } else if (t < 504) {
                int t2 = t - 432;
                int gl = t2 / 9, idx = t2 - gl * 9;
                int g = (gl < 4) ? (c0 + gl) : (c0 + 60 + gl);
                s_wd3b[gl][idx] = w_dw3b[g * 9 + idx];
            } else {
                int gl = t - 504;
                int g = (gl < 4) ? (c0 + gl) : (c0 + 60 + gl);
                s_b1[gl]  = b_dw1[g];
                s_b3a[gl] = b_dw3a[g];
                s_b3b[gl] = b_dw3b[g];
            }
        }

        for (int p = tid; p < R20 * R20; p += 256) {
            int py = p / R20, px = p - py * R20;
            int gy = oy0 - 2 + py, gx = ox0 - 2 + px;
            if ((unsigned)gy >= 256u || (unsigned)gx >= 256u) {
#pragma unroll 1
                for (int l = 0; l < 24; ++l) s_xc[l][p] = 0;
                continue;
            }
            const int off = gy * 256 + gx;
            float xr[64];
            const float* xp = xin + (size_t)b * 64 * HW + off;
#pragma unroll
            for (int c = 0; c < 64; ++c) xr[c] = xp[(size_t)c * HW];
            float p0 = 0.f, p1 = 0.f;
            if (3 * c0 < 128) {
                const float* pp = pnin + (size_t)b * 2 * HW + off;
                p0 = pp[0]; p1 = pp[HW];
            }
#pragma unroll 1
            for (int l = 0; l < 24; ++l) {
                int k = (l < 12) ? (3 * c0 + l) : (3 * c0 + 192 + (l - 12));
                float acc;
                if (k < 128) {
                    acc = b_pn[k] + w_pn[2 * k] * p0 + w_pn[2 * k + 1] * p1;
                } else {
                    int kk = k - 128;
                    acc = b_in[kk];
                    const float2* wr = (const float2*)(w_in + kk * 64);
#pragma unroll
                    for (int i = 0; i < 32; ++i) {
                        float2 w2 = wr[i];
                        acc = fmaf(w2.x, xr[2 * i], acc);
                        acc = fmaf(w2.y, xr[2 * i + 1], acc);
                    }
                }
                s_xc[l][p] = f2bf(acc);
            }
        }
        __syncthreads();

        for (int task = tid; task < 8 * 81; task += 256) {
            int gl = task / 81, patch = task - gl * 81;
            int py = (patch / 9) * 2, px = (patch - (patch / 9) * 9) * 2;
            float bias = s_b3a[gl];
            float a00 = bias, a01 = bias, a10 = bias, a11 = bias;
#pragma unroll
            for (int j = 0; j < 3; ++j) {
                int lc = (gl < 4) ? (3 * gl + j) : (12 + 3 * (gl - 4) + j);
                const u32* base = (const u32*)&s_xc[lc][0];
                float win[4][4];
#pragma unroll
                for (int r = 0; r < 4; ++r) {
                    int e = (py + r) * R20 + px;
                    u32 u0 = base[e >> 1];
                    u32 u1 = base[(e >> 1) + 1];
                    win[r][0] = bflo(u0); win[r][1] = bfhi(u0);
                    win[r][2] = bflo(u1); win[r][3] = bfhi(u1);
                }
#pragma unroll
                for (int ky = 0; ky < 3; ++ky)
#pragma unroll
                    for (int kx = 0; kx < 3; ++kx) {
                        float wgt = s_wd3a[gl][j * 9 + ky * 3 + kx];
                        a00 = fmaf(wgt, win[ky][kx], a00);
                        a01 = fmaf(wgt, win[ky][kx + 1], a01);
                        a10 = fmaf(wgt, win[ky + 1][kx], a10);
                        a11 = fmaf(wgt, win[ky + 1][kx + 1], a11);
                    }
            }
            int gy0 = oy0 - 1 + py, gx0 = ox0 - 1 + px;
            bool vy0 = (unsigned)gy0 < 256u, vy1 = (unsigned)(gy0 + 1) < 256u;
            bool vx0 = (unsigned)gx0 < 256u, vx1 = (unsigned)(gx0 + 1) < 256u;
            float* drow = &s_d3a[gl][py * R18 + px];
            drow[0]       = (vy0 && vx0) ? a00 : 0.f;
            drow[1]       = (vy0 && vx1) ? a01 : 0.f;
            drow[R18]     = (vy1 && vx0) ? a10 : 0.f;
            drow[R18 + 1] = (vy1 && vx1) ? a11 : 0.f;
        }

        for (int task = tid; task < 8 * 64; task += 256) {
            int gl = task >> 6, patch = task & 63;
            int py = (patch >> 3) * 2, px = (patch & 7) * 2;
            float bias = s_b1[gl];
            float a00 = bias, a01 = bias, a10 = bias, a11 = bias;
#pragma unroll
            for (int j = 0; j < 3; ++j) {
                int lc = (gl < 4) ? (3 * gl + j) : (12 + 3 * (gl - 4) + j);
                const u32* base = (const u32*)&s_xc[lc][0];
                float win[4][4];
#pragma unroll
                for (int r = 0; r < 4; ++r) {
                    int e = (py + 1 + r) * R20 + px;
                    u32 u0 = base[e >> 1];
                    u32 u1 = base[(e >> 1) + 1];
                    u32 u2 = base[(e >> 1) + 2];
                    win[r][0] = bfhi(u0); win[r][1] = bflo(u1);
                    win[r][2] = bfhi(u1); win[r][3] = bflo(u2);
                }
#pragma unroll
                for (int ky = 0; ky < 3; ++ky)
#pragma unroll
                    for (int kx = 0; kx < 3; ++kx) {
                        float wgt = s_wd1[gl][j * 9 + ky * 3 + kx];
                        a00 = fmaf(wgt, win[ky][kx], a00);
                        a01 = fmaf(wgt, win[ky][kx + 1], a01);
                        a10 = fmaf(wgt, win[ky + 1][kx], a10);
                        a11 = fmaf(wgt, win[ky + 1][kx + 1], a11);
                    }
            }
            float* drow = &s_d1[gl][py * T + px];
            drow[0] = a00; drow[1] = a01; drow[T] = a10; drow[T + 1] = a11;
        }
        __syncthreads();

        for (int task = tid; task < 8 * 64; task += 256) {
            int gl = task >> 6, patch = task & 63;
            int py = (patch >> 3) * 2, px = (patch & 7) * 2;
            float bias = s_b3b[gl];
            float a00 = bias, a01 = bias, a10 = bias, a11 = bias;
            float win[4][4];
#pragma unroll
            for (int r = 0; r < 4; ++r) {
                int e = (py + r) * R18 + px;
                float2 f0 = *(const float2*)&s_d3a[gl][e];
                float2 f1 = *(const float2*)&s_d3a[gl][e + 2];
                win[r][0] = f0.x; win[r][1] = f0.y;
                win[r][2] = f1.x; win[r][3] = f1.y;
            }
#pragma unroll
            for (int ky = 0; ky < 3; ++ky)
#pragma unroll
                for (int kx = 0; kx < 3; ++kx) {
                    float wgt = s_wd3b[gl][ky * 3 + kx];
                    a00 = fmaf(wgt, win[ky][kx], a00);
                    a01 = fmaf(wgt, win[ky][kx + 1], a01);
                    a10 = fmaf(wgt, win[ky + 1][kx], a10);
                    a11 = fmaf(wgt, win[ky + 1][kx + 1], a11);
                }
            float* drow = &s_d3[gl][py * T + px];
            drow[0] = a00; drow[1] = a01; drow[T] = a10; drow[T + 1] = a11;
        }
        __syncthreads();

#pragma unroll
        for (int jp = 0; jp < 2; ++jp) {
            int j0 = 2 * jp;
            float g1a = gelu_exact(s_d1[j0][tid])     * s_d1[j0 + 4][tid];
            float g1b = gelu_exact(s_d1[j0 + 1][tid]) * s_d1[j0 + 5][tid];
            float g2a = gelu_exact(s_d3[j0][tid])     * s_d3[j0 + 4][tid];
            float g2b = gelu_exact(s_d3[j0 + 1][tid]) * s_d3[j0 + 5][tid];
            int c = c0 + j0;
#pragma unroll
            for (int o = 0; o < 32; ++o) {
                float2 wL = *(const float2*)(w_out + o * 64 + c);
                accL[o] = fmaf(wL.x, g1a, accL[o]);
                accL[o] = fmaf(wL.y, g1b, accL[o]);
                float2 wH = *(const float2*)(w_out + (o + 32) * 64 + c);
                accH[o] = fmaf(wH.x, g2a, accH[o]);
                accH[o] = fmaf(wH.y, g2b, accH[o]);
            }
        }
    }

    {
        int py = tid >> 4, pxx = tid & 15;
        size_t obase = (size_t)b * 64 * HW
                     + (size_t)(oy0 + py) * 256 + (ox0 + pxx);
#pragma unroll
        for (int o = 0; o < 32; ++o) {
            outp[obase + (size_t)o * HW]        = accL[o] + b_out[o];
            outp[obase + (size_t)(o + 32) * HW] = accH[o] + b_out[o + 32];
        }
    }
}

extern "C" void kernel_launch(void* const* d_in, const int* in_sizes, int n_in,
                              void* d_out, int out_size, void* d_ws, size_t ws_size,
                              hipStream_t stream) {
    (void)in_sizes; (void)n_in; (void)out_size;
    const float* xin    = (const float*)d_in[0];
    const float* pnin   = (const float*)d_in[1];
    const float* w_in   = (const float*)d_in[2];
    const float* b_in   = (const float*)d_in[3];
    const float* w_pn   = (const float*)d_in[4];
    const float* b_pn   = (const float*)d_in[5];
    const float* w_dw1  = (const float*)d_in[6];
    const float* b_dw1  = (const float*)d_in[7];
    const float* w_dw3a = (const float*)d_in[8];
    const float* b_dw3a = (const float*)d_in[9];
    const float* w_dw3b = (const float*)d_in[10];
    const float* b_dw3b = (const float*)d_in[11];
    const float* w_out  = (const float*)d_in[12];
    const float* b_out  = (const float*)d_in[13];
    float* outp = (float*)d_out;

    if (ws_size >= XC_BYTES) {
        u16* xc = (u16*)d_ws;
        dim3 g1(128, 4), b1(256);   // 2 pixels/thread
        k1_proj_in<<<g1, b1, 0, stream>>>(xin, pnin, w_in, b_in, w_pn, b_pn, xc);
        dim3 g2(16, 16, 4), b2(512);
        k2_spatial<<<g2, b2, 0, stream>>>(xc, w_dw1, b_dw1, w_dw3a, b_dw3a,
                                          w_dw3b, b_dw3b, w_out, b_out, outp);
    } else {
        dim3 grid(16, 16, 4), blk(256);
        ffd_fused<<<grid, blk, 0, stream>>>(xin, pnin, w_in, b_in, w_pn, b_pn,
                                            w_dw1, b_dw1, w_dw3a, b_dw3a,
                                            w_dw3b, b_dw3b, w_out, b_out, outp);
    }
}